// Round 7
// baseline (331.228 us; speedup 1.0000x reference)
//
#include <hip/hip_runtime.h>
#include <hip/hip_fp16.h>
#include <math.h>

#define H 4
#define HD 16
#define NEG_SLOPE 0.2f
#define EPS_SM 1e-8f
#define EPS_LN 1e-5f
#define PAD 16          // one counter per 64B cache line
#define BSHIFT 5        // bucket = dst >> 5  (32 nodes/bucket)

// ---------------------------------------------------------------------------
// Kernel 1: h = x @ W_node (64x64) + fused a_src/a_dst projections.
// 64 rows per 256-thread block, register-tiled 4x4 per thread.
// h stored as f16 (halves downstream gather traffic).
// ---------------------------------------------------------------------------
__global__ __launch_bounds__(256) void k_node(
    const float* __restrict__ x, const float* __restrict__ Wn,
    const float* __restrict__ attn_src, const float* __restrict__ attn_dst,
    __half* __restrict__ h16, float* __restrict__ a_src, float* __restrict__ a_dst,
    int n)
{
    __shared__ float Ws[64][64];   // W[k][col]
    __shared__ float xs[64][64];   // x[r][k]
    const int tid  = threadIdx.x;
    const int row0 = blockIdx.x * 64;

    const float4* Wn4 = (const float4*)Wn;
    #pragma unroll
    for (int i = tid; i < 1024; i += 256) {
        float4 v = Wn4[i];
        *(float4*)&Ws[i >> 4][(i & 15) * 4] = v;
    }
    const float4* x4 = (const float4*)x;
    #pragma unroll
    for (int i = tid; i < 1024; i += 256) {
        int r  = i >> 4;
        int gr = row0 + r;
        float4 v = (gr < n) ? x4[(size_t)gr * 16 + (i & 15)]
                            : make_float4(0.f, 0.f, 0.f, 0.f);
        *(float4*)&xs[r][(i & 15) * 4] = v;
    }
    __syncthreads();

    const int c4 = tid & 15;   // col group (cols 4c4..4c4+3)
    const int r4 = tid >> 4;   // base row 0..15

    float4 acc0 = make_float4(0.f, 0.f, 0.f, 0.f);
    float4 acc1 = make_float4(0.f, 0.f, 0.f, 0.f);
    float4 acc2 = make_float4(0.f, 0.f, 0.f, 0.f);
    float4 acc3 = make_float4(0.f, 0.f, 0.f, 0.f);

    #pragma unroll 8
    for (int k = 0; k < 64; ++k) {
        float4 w = *(const float4*)&Ws[k][c4 * 4];
        float x0 = xs[r4     ][k];
        float x1 = xs[r4 + 16][k];
        float x2 = xs[r4 + 32][k];
        float x3 = xs[r4 + 48][k];
        acc0.x += x0 * w.x; acc0.y += x0 * w.y; acc0.z += x0 * w.z; acc0.w += x0 * w.w;
        acc1.x += x1 * w.x; acc1.y += x1 * w.y; acc1.z += x1 * w.z; acc1.w += x1 * w.w;
        acc2.x += x2 * w.x; acc2.y += x2 * w.y; acc2.z += x2 * w.z; acc2.w += x2 * w.w;
        acc3.x += x3 * w.x; acc3.y += x3 * w.y; acc3.z += x3 * w.z; acc3.w += x3 * w.w;
    }

    const float4 asw = *(const float4*)&attn_src[c4 * 4];
    const float4 adw = *(const float4*)&attn_dst[c4 * 4];
    const int hh = c4 >> 2;
    const bool writer = (c4 & 3) == 0;

    float4 accs[4] = {acc0, acc1, acc2, acc3};
    #pragma unroll
    for (int j = 0; j < 4; ++j) {
        int gr = row0 + r4 + 16 * j;
        if (gr < n) {
            __half2 p0 = __floats2half2_rn(accs[j].x, accs[j].y);
            __half2 p1 = __floats2half2_rn(accs[j].z, accs[j].w);
            uint2 pk = make_uint2(*reinterpret_cast<unsigned*>(&p0),
                                  *reinterpret_cast<unsigned*>(&p1));
            *(uint2*)&h16[(size_t)gr * 64 + c4 * 4] = pk;
            float ps = accs[j].x * asw.x + accs[j].y * asw.y +
                       accs[j].z * asw.z + accs[j].w * asw.w;
            float pd = accs[j].x * adw.x + accs[j].y * adw.y +
                       accs[j].z * adw.z + accs[j].w * adw.w;
            ps += __shfl_xor(ps, 1, 64); ps += __shfl_xor(ps, 2, 64);
            pd += __shfl_xor(pd, 1, 64); pd += __shfl_xor(pd, 2, 64);
            if (writer) {
                a_src[(size_t)gr * 4 + hh] = ps;
                a_dst[(size_t)gr * 4 + hh] = pd;
            }
        } else {
            float ps = 0.f, pd = 0.f;
            ps += __shfl_xor(ps, 1, 64); ps += __shfl_xor(ps, 2, 64);
            pd += __shfl_xor(pd, 1, 64); pd += __shfl_xor(pd, 2, 64);
        }
    }
}

// ---------------------------------------------------------------------------
// Kernel 2: degree histogram over dst (padded counters).
// ---------------------------------------------------------------------------
__global__ __launch_bounds__(256) void k_hist(
    const int* __restrict__ dst, int* __restrict__ degp, int E)
{
    int e = blockIdx.x * 256 + threadIdx.x;
    if (e < E) atomicAdd(&degp[(size_t)dst[e] * PAD], 1);
}

// ---------------------------------------------------------------------------
// Scan: exclusive prefix sum of degp -> row_start (dense), cursorp (strided),
// and bucket cursors (bcursor[b] = row_start[32b]).
// ---------------------------------------------------------------------------
__global__ __launch_bounds__(256) void k_scan_reduce(
    const int* __restrict__ degp, int* __restrict__ partials, int n)
{
    const int t = threadIdx.x;
    int idx = blockIdx.x * 1024 + t * 4;
    int s = 0;
    #pragma unroll
    for (int k = 0; k < 4; ++k) { int i = idx + k; if (i < n) s += degp[(size_t)i * PAD]; }
    #pragma unroll
    for (int off = 32; off; off >>= 1) s += __shfl_xor(s, off, 64);
    __shared__ int wsum[4];
    if ((t & 63) == 0) wsum[t >> 6] = s;
    __syncthreads();
    if (t == 0) partials[blockIdx.x] = wsum[0] + wsum[1] + wsum[2] + wsum[3];
}

__global__ void k_scan_partials(int* __restrict__ partials, int nb)
{
    int lane = threadIdx.x;
    int i0 = 2 * lane, i1 = 2 * lane + 1;
    int v0 = (i0 < nb) ? partials[i0] : 0;
    int v1 = (i1 < nb) ? partials[i1] : 0;
    int s = v0 + v1;
    int incl = s;
    #pragma unroll
    for (int off = 1; off < 64; off <<= 1) {
        int u = __shfl_up(incl, off, 64);
        if (lane >= off) incl += u;
    }
    int excl = incl - s;
    if (i0 < nb) partials[i0] = excl;
    if (i1 < nb) partials[i1] = excl + v0;
}

__global__ __launch_bounds__(256) void k_scan_final(
    const int* __restrict__ degp, const int* __restrict__ partials,
    int* __restrict__ row_start, int* __restrict__ cursorp,
    int* __restrict__ bcursor, int n)
{
    const int t = threadIdx.x;
    const int lane = t & 63, wid = t >> 6;
    int idx = blockIdx.x * 1024 + t * 4;
    int d0 = (idx     < n) ? degp[(size_t)(idx    ) * PAD] : 0;
    int d1 = (idx + 1 < n) ? degp[(size_t)(idx + 1) * PAD] : 0;
    int d2 = (idx + 2 < n) ? degp[(size_t)(idx + 2) * PAD] : 0;
    int d3 = (idx + 3 < n) ? degp[(size_t)(idx + 3) * PAD] : 0;
    int s = d0 + d1 + d2 + d3;
    int incl = s;
    #pragma unroll
    for (int off = 1; off < 64; off <<= 1) {
        int u = __shfl_up(incl, off, 64);
        if (lane >= off) incl += u;
    }
    __shared__ int wsum[4];
    if (lane == 63) wsum[wid] = incl;
    __syncthreads();
    int woff = 0;
    for (int i = 0; i < wid; ++i) woff += wsum[i];
    int p = partials[blockIdx.x] + woff + (incl - s);
    // idx is a multiple of 4, so only idx itself can be a bucket boundary
    if (idx     < n) { row_start[idx    ] = p; cursorp[(size_t)(idx    ) * PAD] = p;
                       if ((idx & 31) == 0) bcursor[(size_t)(idx >> BSHIFT) * PAD] = p; } p += d0;
    if (idx + 1 < n) { row_start[idx + 1] = p; cursorp[(size_t)(idx + 1) * PAD] = p; } p += d1;
    if (idx + 2 < n) { row_start[idx + 2] = p; cursorp[(size_t)(idx + 2) * PAD] = p; } p += d2;
    if (idx + 3 < n) { row_start[idx + 3] = p; cursorp[(size_t)(idx + 3) * PAD] = p; }
}

// ---------------------------------------------------------------------------
// Kernel 3a (pass 1): compute record {src, f16x2(as01+esc01), f16x2(as23+esc23),
// dst} and APPEND into the record's bucket region of csr_tmp. Bucket regions
// are the final CSR ranges [row_start[32b], row_start[32b+32]) — append heads
// advance sequentially => dense full-line writes.
// ---------------------------------------------------------------------------
__global__ __launch_bounds__(256) void k_perm_pass1(
    const int* __restrict__ src, const int* __restrict__ dst,
    const float* __restrict__ ea, const float* __restrict__ We,
    const float* __restrict__ a_src,
    int* __restrict__ bcursor, int4* __restrict__ csr_tmp, int E)
{
    __shared__ float Wes[64];   // W_edge [16][4]
    const int tid = threadIdx.x;
    if (tid < 64) Wes[tid] = We[tid];
    __syncthreads();

    int e = blockIdx.x * 256 + tid;
    if (e >= E) return;

    int d = dst[e];
    int pos = atomicAdd(&bcursor[(size_t)(d >> BSHIFT) * PAD], 1);  // issue early
    int s = src[e];
    float4 as4 = *(const float4*)(a_src + (size_t)s * 4);           // L2-resident

    const float4* ea4 = (const float4*)(ea + (size_t)e * 16);
    float4 v0 = ea4[0], v1 = ea4[1], v2 = ea4[2], v3 = ea4[3];
    float eav[16] = {v0.x, v0.y, v0.z, v0.w, v1.x, v1.y, v1.z, v1.w,
                     v2.x, v2.y, v2.z, v2.w, v3.x, v3.y, v3.z, v3.w};
    float esc[H] = {0.f, 0.f, 0.f, 0.f};
    #pragma unroll
    for (int k = 0; k < 16; ++k) {
        #pragma unroll
        for (int hh = 0; hh < H; ++hh) esc[hh] += eav[k] * Wes[k * 4 + hh];
    }

    __half2 p01 = __floats2half2_rn(as4.x + esc[0], as4.y + esc[1]);
    __half2 p23 = __floats2half2_rn(as4.z + esc[2], as4.w + esc[3]);
    int y = *reinterpret_cast<int*>(&p01);
    int z = *reinterpret_cast<int*>(&p23);

    csr_tmp[pos] = make_int4(s, y, z, d);
}

// ---------------------------------------------------------------------------
// Kernel 3b (pass 2): stream bucket-grouped records, place each at its node's
// final slot. Writes are random only within an ~8KB L2-hot window per bucket.
// ---------------------------------------------------------------------------
__global__ __launch_bounds__(256) void k_perm_pass2(
    const int4* __restrict__ csr_tmp, int* __restrict__ cursorp,
    int4* __restrict__ csr, int E)
{
    int e = blockIdx.x * 256 + threadIdx.x;
    if (e >= E) return;
    int4 rec = csr_tmp[e];
    int pos = atomicAdd(&cursorp[(size_t)rec.w * PAD], 1);
    csr[pos] = rec;
}

// ---------------------------------------------------------------------------
// Kernel 4: wave-per-node aggregation + residual + LayerNorm. h in f16.
// ---------------------------------------------------------------------------
__global__ __launch_bounds__(256) void k_aggregate_ln(
    const int* __restrict__ row_start, const int* __restrict__ degp,
    const int4* __restrict__ csr, const __half* __restrict__ h16,
    const float* __restrict__ a_dst,
    const float* __restrict__ gamma, const float* __restrict__ beta,
    float* __restrict__ out, int n)
{
    int gid  = blockIdx.x * 256 + threadIdx.x;
    int node = gid >> 6;
    int lane = gid & 63;
    if (node >= n) return;
    const int hh   = lane >> 4;
    const int hilo = hh & 1;

    const int rs = row_start[node];
    const int dg = degp[(size_t)node * PAD];

    const float h_node = __half2float(h16[(size_t)node * 64 + lane]);
    float4 ad4 = *(const float4*)(a_dst + (size_t)node * 4);
    const float ad = (hh == 0) ? ad4.x : (hh == 1) ? ad4.y : (hh == 2) ? ad4.z : ad4.w;

    float sum = 0.f, accv = 0.f;

#define PROC_EDGE(HV, YW, ZW)                                            \
    {                                                                    \
        int w_ = (hh < 2) ? (YW) : (ZW);                                 \
        float2 f2_ = __half22float2(*reinterpret_cast<__half2*>(&w_));   \
        float a_ = (hilo ? f2_.y : f2_.x) + ad;                          \
        a_ = (a_ >= 0.f) ? a_ : NEG_SLOPE * a_;                          \
        float w2_ = __expf(a_);                                          \
        sum  += w2_;                                                     \
        accv += w2_ * (HV);                                              \
    }

    for (int base = 0; base < dg; base += 64) {
        int cnt = min(64, dg - base);
        int4 myc = (base + lane < dg) ? csr[(size_t)rs + base + lane]
                                      : make_int4(0, 0, 0, 0);
        int i = 0;
        for (; i + 4 <= cnt; i += 4) {
            int s0 = __shfl(myc.x, i + 0, 64);
            int s1 = __shfl(myc.x, i + 1, 64);
            int s2 = __shfl(myc.x, i + 2, 64);
            int s3 = __shfl(myc.x, i + 3, 64);
            int y0 = __shfl(myc.y, i + 0, 64), z0 = __shfl(myc.z, i + 0, 64);
            int y1 = __shfl(myc.y, i + 1, 64), z1 = __shfl(myc.z, i + 1, 64);
            int y2 = __shfl(myc.y, i + 2, 64), z2 = __shfl(myc.z, i + 2, 64);
            int y3 = __shfl(myc.y, i + 3, 64), z3 = __shfl(myc.z, i + 3, 64);
            float hv0 = __half2float(h16[(size_t)s0 * 64 + lane]);
            float hv1 = __half2float(h16[(size_t)s1 * 64 + lane]);
            float hv2 = __half2float(h16[(size_t)s2 * 64 + lane]);
            float hv3 = __half2float(h16[(size_t)s3 * 64 + lane]);
            PROC_EDGE(hv0, y0, z0);
            PROC_EDGE(hv1, y1, z1);
            PROC_EDGE(hv2, y2, z2);
            PROC_EDGE(hv3, y3, z3);
        }
        for (; i < cnt; ++i) {
            int s0 = __shfl(myc.x, i, 64);
            int y0 = __shfl(myc.y, i, 64);
            int z0 = __shfl(myc.z, i, 64);
            float hv0 = __half2float(h16[(size_t)s0 * 64 + lane]);
            PROC_EDGE(hv0, y0, z0);
        }
    }
#undef PROC_EDGE

    float y = accv / (sum + EPS_SM) + h_node;

    float t1 = y;
    #pragma unroll
    for (int off = 32; off; off >>= 1) t1 += __shfl_xor(t1, off, 64);
    float mu = t1 * (1.f / 64.f);
    float dv = y - mu;
    float vs = dv * dv;
    #pragma unroll
    for (int off = 32; off; off >>= 1) vs += __shfl_xor(vs, off, 64);
    float var = vs * (1.f / 64.f);
    out[(size_t)node * 64 + lane] = dv * rsqrtf(var + EPS_LN) * gamma[lane] + beta[lane];
}

// ---------------------------------------------------------------------------
extern "C" void kernel_launch(void* const* d_in, const int* in_sizes, int n_in,
                              void* d_out, int out_size, void* d_ws, size_t ws_size,
                              hipStream_t stream)
{
    const float* x     = (const float*)d_in[0];
    const int*   ei    = (const int*)  d_in[1];
    const float* ea    = (const float*)d_in[2];
    const float* Wn    = (const float*)d_in[3];
    const float* We    = (const float*)d_in[4];
    const float* asrcW = (const float*)d_in[5];
    const float* adstW = (const float*)d_in[6];
    const float* gamma = (const float*)d_in[7];
    const float* beta  = (const float*)d_in[8];
    float* out = (float*)d_out;

    const int n = in_sizes[0] / 64;
    const int E = in_sizes[1] / 2;
    const int* src = ei;
    const int* dst = ei + E;
    const int nb = (n + 1023) / 1024;
    const int nbkt = (n + 31) >> BSHIFT;

    float* ws = (float*)d_ws;
    size_t off = 0;
    __half* h16  = (__half*)(ws + off); off += (size_t)n * 32;   // n*64 halves
    float* a_src = ws + off; off += (size_t)n * 4;
    float* a_dst = ws + off; off += (size_t)n * 4;
    int4* csr_tmp = (int4*)(ws + off); off += (size_t)E * 4;
    int4* csr     = (int4*)(ws + off); off += (size_t)E * 4;
    int* ibase     = (int*)(ws + off);
    int* degp      = ibase;                               // n*PAD
    int* cursorp   = ibase + (size_t)n * PAD;             // n*PAD
    int* bcursor   = ibase + 2 * (size_t)n * PAD;         // nbkt*PAD
    int* row_start = ibase + 2 * (size_t)n * PAD + (size_t)nbkt * PAD;  // n
    int* partials  = row_start + n;                       // nb

    hipMemsetAsync(degp, 0, (size_t)n * PAD * sizeof(int), stream);

    k_node<<<(n + 63) / 64, 256, 0, stream>>>(x, Wn, asrcW, adstW, h16, a_src, a_dst, n);
    k_hist<<<(E + 255) / 256, 256, 0, stream>>>(dst, degp, E);
    k_scan_reduce<<<nb, 256, 0, stream>>>(degp, partials, n);
    k_scan_partials<<<1, 64, 0, stream>>>(partials, nb);
    k_scan_final<<<nb, 256, 0, stream>>>(degp, partials, row_start, cursorp, bcursor, n);
    k_perm_pass1<<<(E + 255) / 256, 256, 0, stream>>>(src, dst, ea, We, a_src,
                                                      bcursor, csr_tmp, E);
    k_perm_pass2<<<(E + 255) / 256, 256, 0, stream>>>(csr_tmp, cursorp, csr, E);
    k_aggregate_ln<<<((size_t)n * 64 + 255) / 256, 256, 0, stream>>>(
        row_start, degp, csr, h16, a_dst, gamma, beta, out, n);
}

// Round 8
// 275.715 us; speedup vs baseline: 1.2013x; 1.2013x over previous
//
#include <hip/hip_runtime.h>
#include <hip/hip_fp16.h>
#include <math.h>

#define H 4
#define HD 16
#define NEG_SLOPE 0.2f
#define EPS_SM 1e-8f
#define EPS_LN 1e-5f
#define PAD 16   // one counter per 64B cache line

// ---------------------------------------------------------------------------
// Kernel 1: h = x @ W_node (64x64) + fused a_src/a_dst projections.
// 64 rows per 256-thread block, register-tiled 4x4 per thread. h stored f16.
// ---------------------------------------------------------------------------
__global__ __launch_bounds__(256) void k_node(
    const float* __restrict__ x, const float* __restrict__ Wn,
    const float* __restrict__ attn_src, const float* __restrict__ attn_dst,
    __half* __restrict__ h16, float* __restrict__ a_src, float* __restrict__ a_dst,
    int n)
{
    __shared__ float Ws[64][64];   // W[k][col]
    __shared__ float xs[64][64];   // x[r][k]
    const int tid  = threadIdx.x;
    const int row0 = blockIdx.x * 64;

    const float4* Wn4 = (const float4*)Wn;
    #pragma unroll
    for (int i = tid; i < 1024; i += 256) {
        float4 v = Wn4[i];
        *(float4*)&Ws[i >> 4][(i & 15) * 4] = v;
    }
    const float4* x4 = (const float4*)x;
    #pragma unroll
    for (int i = tid; i < 1024; i += 256) {
        int r  = i >> 4;
        int gr = row0 + r;
        float4 v = (gr < n) ? x4[(size_t)gr * 16 + (i & 15)]
                            : make_float4(0.f, 0.f, 0.f, 0.f);
        *(float4*)&xs[r][(i & 15) * 4] = v;
    }
    __syncthreads();

    const int c4 = tid & 15;
    const int r4 = tid >> 4;

    float4 acc0 = make_float4(0.f, 0.f, 0.f, 0.f);
    float4 acc1 = make_float4(0.f, 0.f, 0.f, 0.f);
    float4 acc2 = make_float4(0.f, 0.f, 0.f, 0.f);
    float4 acc3 = make_float4(0.f, 0.f, 0.f, 0.f);

    #pragma unroll 8
    for (int k = 0; k < 64; ++k) {
        float4 w = *(const float4*)&Ws[k][c4 * 4];
        float x0 = xs[r4     ][k];
        float x1 = xs[r4 + 16][k];
        float x2 = xs[r4 + 32][k];
        float x3 = xs[r4 + 48][k];
        acc0.x += x0 * w.x; acc0.y += x0 * w.y; acc0.z += x0 * w.z; acc0.w += x0 * w.w;
        acc1.x += x1 * w.x; acc1.y += x1 * w.y; acc1.z += x1 * w.z; acc1.w += x1 * w.w;
        acc2.x += x2 * w.x; acc2.y += x2 * w.y; acc2.z += x2 * w.z; acc2.w += x2 * w.w;
        acc3.x += x3 * w.x; acc3.y += x3 * w.y; acc3.z += x3 * w.z; acc3.w += x3 * w.w;
    }

    const float4 asw = *(const float4*)&attn_src[c4 * 4];
    const float4 adw = *(const float4*)&attn_dst[c4 * 4];
    const int hh = c4 >> 2;
    const bool writer = (c4 & 3) == 0;

    float4 accs[4] = {acc0, acc1, acc2, acc3};
    #pragma unroll
    for (int j = 0; j < 4; ++j) {
        int gr = row0 + r4 + 16 * j;
        if (gr < n) {
            __half2 p0 = __floats2half2_rn(accs[j].x, accs[j].y);
            __half2 p1 = __floats2half2_rn(accs[j].z, accs[j].w);
            uint2 pk = make_uint2(*reinterpret_cast<unsigned*>(&p0),
                                  *reinterpret_cast<unsigned*>(&p1));
            *(uint2*)&h16[(size_t)gr * 64 + c4 * 4] = pk;
            float ps = accs[j].x * asw.x + accs[j].y * asw.y +
                       accs[j].z * asw.z + accs[j].w * asw.w;
            float pd = accs[j].x * adw.x + accs[j].y * adw.y +
                       accs[j].z * adw.z + accs[j].w * adw.w;
            ps += __shfl_xor(ps, 1, 64); ps += __shfl_xor(ps, 2, 64);
            pd += __shfl_xor(pd, 1, 64); pd += __shfl_xor(pd, 2, 64);
            if (writer) {
                a_src[(size_t)gr * 4 + hh] = ps;
                a_dst[(size_t)gr * 4 + hh] = pd;
            }
        } else {
            float ps = 0.f, pd = 0.f;
            ps += __shfl_xor(ps, 1, 64); ps += __shfl_xor(ps, 2, 64);
            pd += __shfl_xor(pd, 1, 64); pd += __shfl_xor(pd, 2, 64);
        }
    }
}

// ---------------------------------------------------------------------------
// Kernel 2: degree histogram over dst (padded counters).
// ---------------------------------------------------------------------------
__global__ __launch_bounds__(256) void k_hist(
    const int* __restrict__ dst, int* __restrict__ degp, int E)
{
    int e = blockIdx.x * 256 + threadIdx.x;
    if (e < E) atomicAdd(&degp[(size_t)dst[e] * PAD], 1);
}

// ---------------------------------------------------------------------------
// Scan: exclusive prefix sum of degp -> row_start (dense) + cursorp (strided).
// ---------------------------------------------------------------------------
__global__ __launch_bounds__(256) void k_scan_reduce(
    const int* __restrict__ degp, int* __restrict__ partials, int n)
{
    const int t = threadIdx.x;
    int idx = blockIdx.x * 1024 + t * 4;
    int s = 0;
    #pragma unroll
    for (int k = 0; k < 4; ++k) { int i = idx + k; if (i < n) s += degp[(size_t)i * PAD]; }
    #pragma unroll
    for (int off = 32; off; off >>= 1) s += __shfl_xor(s, off, 64);
    __shared__ int wsum[4];
    if ((t & 63) == 0) wsum[t >> 6] = s;
    __syncthreads();
    if (t == 0) partials[blockIdx.x] = wsum[0] + wsum[1] + wsum[2] + wsum[3];
}

__global__ void k_scan_partials(int* __restrict__ partials, int nb)
{
    int lane = threadIdx.x;
    int i0 = 2 * lane, i1 = 2 * lane + 1;
    int v0 = (i0 < nb) ? partials[i0] : 0;
    int v1 = (i1 < nb) ? partials[i1] : 0;
    int s = v0 + v1;
    int incl = s;
    #pragma unroll
    for (int off = 1; off < 64; off <<= 1) {
        int u = __shfl_up(incl, off, 64);
        if (lane >= off) incl += u;
    }
    int excl = incl - s;
    if (i0 < nb) partials[i0] = excl;
    if (i1 < nb) partials[i1] = excl + v0;
}

__global__ __launch_bounds__(256) void k_scan_final(
    const int* __restrict__ degp, const int* __restrict__ partials,
    int* __restrict__ row_start, int* __restrict__ cursorp, int n)
{
    const int t = threadIdx.x;
    const int lane = t & 63, wid = t >> 6;
    int idx = blockIdx.x * 1024 + t * 4;
    int d0 = (idx     < n) ? degp[(size_t)(idx    ) * PAD] : 0;
    int d1 = (idx + 1 < n) ? degp[(size_t)(idx + 1) * PAD] : 0;
    int d2 = (idx + 2 < n) ? degp[(size_t)(idx + 2) * PAD] : 0;
    int d3 = (idx + 3 < n) ? degp[(size_t)(idx + 3) * PAD] : 0;
    int s = d0 + d1 + d2 + d3;
    int incl = s;
    #pragma unroll
    for (int off = 1; off < 64; off <<= 1) {
        int u = __shfl_up(incl, off, 64);
        if (lane >= off) incl += u;
    }
    __shared__ int wsum[4];
    if (lane == 63) wsum[wid] = incl;
    __syncthreads();
    int woff = 0;
    for (int i = 0; i < wid; ++i) woff += wsum[i];
    int p = partials[blockIdx.x] + woff + (incl - s);
    if (idx     < n) { row_start[idx    ] = p; cursorp[(size_t)(idx    ) * PAD] = p; } p += d0;
    if (idx + 1 < n) { row_start[idx + 1] = p; cursorp[(size_t)(idx + 1) * PAD] = p; } p += d1;
    if (idx + 2 < n) { row_start[idx + 2] = p; cursorp[(size_t)(idx + 2) * PAD] = p; } p += d2;
    if (idx + 3 < n) { row_start[idx + 3] = p; cursorp[(size_t)(idx + 3) * PAD] = p; }
}

// ---------------------------------------------------------------------------
// Kernel 3: CSR build, 4 edges per thread for 4x memory-level parallelism.
// Edges {base+t, +256, +512, +768}: all loads coalesced per wave; the 4
// atomicAdd chains are issued back-to-back so their ~600cy returns overlap;
// then 4 independent a_src gathers, 4 ea reads, 4 scattered stores.
// Record: int4 { src, f16x2(as0+esc0, as1+esc1), f16x2(as2+esc2, as3+esc3), 0 }.
// ---------------------------------------------------------------------------
__global__ __launch_bounds__(256) void k_perm_build(
    const int* __restrict__ src, const int* __restrict__ dst,
    const float* __restrict__ ea, const float* __restrict__ We,
    const float* __restrict__ a_src,
    int* __restrict__ cursorp, int4* __restrict__ csr, int E)
{
    __shared__ float Wes[64];   // W_edge [16][4]
    const int tid = threadIdx.x;
    if (tid < 64) Wes[tid] = We[tid];
    __syncthreads();

    const int base = blockIdx.x * 1024 + tid;
    int e[4];
    bool v[4];
    #pragma unroll
    for (int j = 0; j < 4; ++j) { e[j] = base + 256 * j; v[j] = e[j] < E; }

    // coalesced dst loads, then all atomics in flight
    int d[4], pos[4];
    #pragma unroll
    for (int j = 0; j < 4; ++j) d[j] = v[j] ? dst[e[j]] : 0;
    #pragma unroll
    for (int j = 0; j < 4; ++j)
        pos[j] = v[j] ? atomicAdd(&cursorp[(size_t)d[j] * PAD], 1) : 0;

    // coalesced src loads, then 4 independent a_src gathers
    int s[4];
    #pragma unroll
    for (int j = 0; j < 4; ++j) s[j] = v[j] ? src[e[j]] : 0;
    float4 as4[4];
    #pragma unroll
    for (int j = 0; j < 4; ++j)
        as4[j] = v[j] ? *(const float4*)(a_src + (size_t)s[j] * 4)
                      : make_float4(0.f, 0.f, 0.f, 0.f);

    #pragma unroll
    for (int j = 0; j < 4; ++j) {
        if (!v[j]) continue;
        const float4* ea4 = (const float4*)(ea + (size_t)e[j] * 16);
        float4 q0 = ea4[0], q1 = ea4[1], q2 = ea4[2], q3 = ea4[3];
        float eav[16] = {q0.x, q0.y, q0.z, q0.w, q1.x, q1.y, q1.z, q1.w,
                         q2.x, q2.y, q2.z, q2.w, q3.x, q3.y, q3.z, q3.w};
        float esc[H] = {0.f, 0.f, 0.f, 0.f};
        #pragma unroll
        for (int k = 0; k < 16; ++k) {
            #pragma unroll
            for (int hh = 0; hh < H; ++hh) esc[hh] += eav[k] * Wes[k * 4 + hh];
        }
        __half2 p01 = __floats2half2_rn(as4[j].x + esc[0], as4[j].y + esc[1]);
        __half2 p23 = __floats2half2_rn(as4[j].z + esc[2], as4[j].w + esc[3]);
        int y = *reinterpret_cast<int*>(&p01);
        int z = *reinterpret_cast<int*>(&p23);
        csr[pos[j]] = make_int4(s[j], y, z, 0);
    }
}

// ---------------------------------------------------------------------------
// Kernel 4: wave-per-node aggregation + residual + LayerNorm. h in f16.
// 8x unrolled gather loop: 8 independent h-row gathers in flight per wave.
// ---------------------------------------------------------------------------
__global__ __launch_bounds__(256) void k_aggregate_ln(
    const int* __restrict__ row_start, const int* __restrict__ degp,
    const int4* __restrict__ csr, const __half* __restrict__ h16,
    const float* __restrict__ a_dst,
    const float* __restrict__ gamma, const float* __restrict__ beta,
    float* __restrict__ out, int n)
{
    int gid  = blockIdx.x * 256 + threadIdx.x;
    int node = gid >> 6;
    int lane = gid & 63;
    if (node >= n) return;
    const int hh   = lane >> 4;
    const int hilo = hh & 1;

    const int rs = row_start[node];
    const int dg = degp[(size_t)node * PAD];

    const float h_node = __half2float(h16[(size_t)node * 64 + lane]);
    float4 ad4 = *(const float4*)(a_dst + (size_t)node * 4);
    const float ad = (hh == 0) ? ad4.x : (hh == 1) ? ad4.y : (hh == 2) ? ad4.z : ad4.w;

    float sum = 0.f, accv = 0.f;

#define PROC_EDGE(HV, YW, ZW)                                            \
    {                                                                    \
        int w_ = (hh < 2) ? (YW) : (ZW);                                 \
        float2 f2_ = __half22float2(*reinterpret_cast<__half2*>(&w_));   \
        float a_ = (hilo ? f2_.y : f2_.x) + ad;                          \
        a_ = (a_ >= 0.f) ? a_ : NEG_SLOPE * a_;                          \
        float w2_ = __expf(a_);                                          \
        sum  += w2_;                                                     \
        accv += w2_ * (HV);                                              \
    }

    for (int base = 0; base < dg; base += 64) {
        int cnt = min(64, dg - base);
        int4 myc = (base + lane < dg) ? csr[(size_t)rs + base + lane]
                                      : make_int4(0, 0, 0, 0);
        int i = 0;
        for (; i + 8 <= cnt; i += 8) {
            int sj[8], yj[8], zj[8];
            float hv[8];
            #pragma unroll
            for (int j = 0; j < 8; ++j) {
                sj[j] = __shfl(myc.x, i + j, 64);
                yj[j] = __shfl(myc.y, i + j, 64);
                zj[j] = __shfl(myc.z, i + j, 64);
            }
            #pragma unroll
            for (int j = 0; j < 8; ++j)
                hv[j] = __half2float(h16[(size_t)sj[j] * 64 + lane]);
            #pragma unroll
            for (int j = 0; j < 8; ++j) PROC_EDGE(hv[j], yj[j], zj[j]);
        }
        for (; i < cnt; ++i) {
            int s0 = __shfl(myc.x, i, 64);
            int y0 = __shfl(myc.y, i, 64);
            int z0 = __shfl(myc.z, i, 64);
            float hv0 = __half2float(h16[(size_t)s0 * 64 + lane]);
            PROC_EDGE(hv0, y0, z0);
        }
    }
#undef PROC_EDGE

    float y = accv / (sum + EPS_SM) + h_node;

    float t1 = y;
    #pragma unroll
    for (int off = 32; off; off >>= 1) t1 += __shfl_xor(t1, off, 64);
    float mu = t1 * (1.f / 64.f);
    float dv = y - mu;
    float vs = dv * dv;
    #pragma unroll
    for (int off = 32; off; off >>= 1) vs += __shfl_xor(vs, off, 64);
    float var = vs * (1.f / 64.f);
    out[(size_t)node * 64 + lane] = dv * rsqrtf(var + EPS_LN) * gamma[lane] + beta[lane];
}

// ---------------------------------------------------------------------------
extern "C" void kernel_launch(void* const* d_in, const int* in_sizes, int n_in,
                              void* d_out, int out_size, void* d_ws, size_t ws_size,
                              hipStream_t stream)
{
    const float* x     = (const float*)d_in[0];
    const int*   ei    = (const int*)  d_in[1];
    const float* ea    = (const float*)d_in[2];
    const float* Wn    = (const float*)d_in[3];
    const float* We    = (const float*)d_in[4];
    const float* asrcW = (const float*)d_in[5];
    const float* adstW = (const float*)d_in[6];
    const float* gamma = (const float*)d_in[7];
    const float* beta  = (const float*)d_in[8];
    float* out = (float*)d_out;

    const int n = in_sizes[0] / 64;
    const int E = in_sizes[1] / 2;
    const int* src = ei;
    const int* dst = ei + E;
    const int nb = (n + 1023) / 1024;

    float* ws = (float*)d_ws;
    size_t off = 0;
    __half* h16  = (__half*)(ws + off); off += (size_t)n * 32;   // n*64 halves
    float* a_src = ws + off; off += (size_t)n * 4;
    float* a_dst = ws + off; off += (size_t)n * 4;
    int4* csr    = (int4*)(ws + off); off += (size_t)E * 4;
    int* ibase     = (int*)(ws + off);
    int* degp      = ibase;                          // n*PAD
    int* cursorp   = ibase + (size_t)n * PAD;        // n*PAD
    int* row_start = ibase + 2 * (size_t)n * PAD;    // n
    int* partials  = row_start + n;                  // nb

    hipMemsetAsync(degp, 0, (size_t)n * PAD * sizeof(int), stream);

    k_node<<<(n + 63) / 64, 256, 0, stream>>>(x, Wn, asrcW, adstW, h16, a_src, a_dst, n);
    k_hist<<<(E + 255) / 256, 256, 0, stream>>>(dst, degp, E);
    k_scan_reduce<<<nb, 256, 0, stream>>>(degp, partials, n);
    k_scan_partials<<<1, 64, 0, stream>>>(partials, nb);
    k_scan_final<<<nb, 256, 0, stream>>>(degp, partials, row_start, cursorp, n);
    k_perm_build<<<(E + 1023) / 1024, 256, 0, stream>>>(src, dst, ea, We, a_src,
                                                        cursorp, csr, E);
    k_aggregate_ln<<<((size_t)n * 64 + 255) / 256, 256, 0, stream>>>(
        row_start, degp, csr, h16, a_dst, gamma, beta, out, n);
}

// Round 9
// 251.058 us; speedup vs baseline: 1.3193x; 1.0982x over previous
//
#include <hip/hip_runtime.h>
#include <hip/hip_fp16.h>
#include <math.h>

#define NEG_SLOPE 0.2f
#define EPS_SM 1e-8f
#define EPS_LN 1e-5f
#define PAD 16          // one global counter per 64B line
#define BSH 8           // bucket = dst >> 8  (256 nodes/bucket)
#define NBMAX 512       // max buckets (n <= 131072)
#define CHUNK 2048      // edges per pass1/bhist block

// ---------------------------------------------------------------------------
// Kernel 1: h = x @ W_node (64x64) + fused a_src/a_dst projections.
// 64 rows per 256-thread block, register-tiled 4x4 per thread. h stored f16.
// ---------------------------------------------------------------------------
__global__ __launch_bounds__(256) void k_node(
    const float* __restrict__ x, const float* __restrict__ Wn,
    const float* __restrict__ attn_src, const float* __restrict__ attn_dst,
    __half* __restrict__ h16, float* __restrict__ a_src, float* __restrict__ a_dst,
    int n)
{
    __shared__ float Ws[64][64];   // W[k][col]
    __shared__ float xs[64][64];   // x[r][k]
    const int tid  = threadIdx.x;
    const int row0 = blockIdx.x * 64;

    const float4* Wn4 = (const float4*)Wn;
    #pragma unroll
    for (int i = tid; i < 1024; i += 256) {
        float4 v = Wn4[i];
        *(float4*)&Ws[i >> 4][(i & 15) * 4] = v;
    }
    const float4* x4 = (const float4*)x;
    #pragma unroll
    for (int i = tid; i < 1024; i += 256) {
        int r  = i >> 4;
        int gr = row0 + r;
        float4 v = (gr < n) ? x4[(size_t)gr * 16 + (i & 15)]
                            : make_float4(0.f, 0.f, 0.f, 0.f);
        *(float4*)&xs[r][(i & 15) * 4] = v;
    }
    __syncthreads();

    const int c4 = tid & 15;
    const int r4 = tid >> 4;

    float4 acc0 = make_float4(0.f, 0.f, 0.f, 0.f);
    float4 acc1 = make_float4(0.f, 0.f, 0.f, 0.f);
    float4 acc2 = make_float4(0.f, 0.f, 0.f, 0.f);
    float4 acc3 = make_float4(0.f, 0.f, 0.f, 0.f);

    #pragma unroll 8
    for (int k = 0; k < 64; ++k) {
        float4 w = *(const float4*)&Ws[k][c4 * 4];
        float x0 = xs[r4     ][k];
        float x1 = xs[r4 + 16][k];
        float x2 = xs[r4 + 32][k];
        float x3 = xs[r4 + 48][k];
        acc0.x += x0 * w.x; acc0.y += x0 * w.y; acc0.z += x0 * w.z; acc0.w += x0 * w.w;
        acc1.x += x1 * w.x; acc1.y += x1 * w.y; acc1.z += x1 * w.z; acc1.w += x1 * w.w;
        acc2.x += x2 * w.x; acc2.y += x2 * w.y; acc2.z += x2 * w.z; acc2.w += x2 * w.w;
        acc3.x += x3 * w.x; acc3.y += x3 * w.y; acc3.z += x3 * w.z; acc3.w += x3 * w.w;
    }

    const float4 asw = *(const float4*)&attn_src[c4 * 4];
    const float4 adw = *(const float4*)&attn_dst[c4 * 4];
    const int hh = c4 >> 2;
    const bool writer = (c4 & 3) == 0;

    float4 accs[4] = {acc0, acc1, acc2, acc3};
    #pragma unroll
    for (int j = 0; j < 4; ++j) {
        int gr = row0 + r4 + 16 * j;
        if (gr < n) {
            __half2 p0 = __floats2half2_rn(accs[j].x, accs[j].y);
            __half2 p1 = __floats2half2_rn(accs[j].z, accs[j].w);
            uint2 pk = make_uint2(*reinterpret_cast<unsigned*>(&p0),
                                  *reinterpret_cast<unsigned*>(&p1));
            *(uint2*)&h16[(size_t)gr * 64 + c4 * 4] = pk;
            float ps = accs[j].x * asw.x + accs[j].y * asw.y +
                       accs[j].z * asw.z + accs[j].w * asw.w;
            float pd = accs[j].x * adw.x + accs[j].y * adw.y +
                       accs[j].z * adw.z + accs[j].w * adw.w;
            ps += __shfl_xor(ps, 1, 64); ps += __shfl_xor(ps, 2, 64);
            pd += __shfl_xor(pd, 1, 64); pd += __shfl_xor(pd, 2, 64);
            if (writer) {
                a_src[(size_t)gr * 4 + hh] = ps;
                a_dst[(size_t)gr * 4 + hh] = pd;
            }
        } else {
            float ps = 0.f, pd = 0.f;
            ps += __shfl_xor(ps, 1, 64); ps += __shfl_xor(ps, 2, 64);
            pd += __shfl_xor(pd, 1, 64); pd += __shfl_xor(pd, 2, 64);
        }
    }
}

// ---------------------------------------------------------------------------
// Kernel 2: bucket histogram (LDS-staged, one global add per (chunk,bucket)).
// ---------------------------------------------------------------------------
__global__ __launch_bounds__(256) void k_bhist(
    const int* __restrict__ dst, int* __restrict__ gbcnt, int E)
{
    __shared__ int cnt[NBMAX];
    const int tid = threadIdx.x;
    for (int i = tid; i < NBMAX; i += 256) cnt[i] = 0;
    __syncthreads();
    const int e0 = blockIdx.x * CHUNK;
    const int ce = min(CHUNK, E - e0);
    for (int j = tid; j < ce; j += 256)
        atomicAdd(&cnt[((unsigned)dst[e0 + j]) >> BSH], 1);
    __syncthreads();
    for (int b = tid; b < NBMAX; b += 256)
        if (cnt[b] > 0) atomicAdd(&gbcnt[b * PAD], cnt[b]);
}

// ---------------------------------------------------------------------------
// Kernel 3: exclusive scan of 512 bucket counts (one wave).
// ---------------------------------------------------------------------------
__global__ void k_bscan(const int* __restrict__ gbcnt,
                        int* __restrict__ bstart, int* __restrict__ bcount,
                        int* __restrict__ bcur)
{
    int lane = threadIdx.x;   // 64 threads
    int c[8]; int s = 0;
    #pragma unroll
    for (int j = 0; j < 8; ++j) { c[j] = gbcnt[(lane * 8 + j) * PAD]; s += c[j]; }
    int incl = s;
    #pragma unroll
    for (int off = 1; off < 64; off <<= 1) {
        int u = __shfl_up(incl, off, 64);
        if (lane >= off) incl += u;
    }
    int run = incl - s;
    #pragma unroll
    for (int j = 0; j < 8; ++j) {
        int b = lane * 8 + j;
        bstart[b] = run;
        bcount[b] = c[j];
        bcur[b * PAD] = run;
        run += c[j];
    }
}

// ---------------------------------------------------------------------------
// Kernel 4: chunk-sorted bucket scatter (dense-run writes).
// Per 2048-edge chunk: compute records {src, f16x2(as01+esc01),
// f16x2(as23+esc23), dst} into LDS, counting-sort by bucket (rank via LDS
// atomics + wave scan), reserve per-bucket global segments, flush contiguous
// runs (avg ~5.2 records) + 1B dl8 side-array for the aggregator.
// ---------------------------------------------------------------------------
__global__ __launch_bounds__(256) void k_pass1(
    const int* __restrict__ src, const int* __restrict__ dst,
    const float* __restrict__ ea, const float* __restrict__ We,
    const float* __restrict__ a_src,
    int* __restrict__ bcur, int4* __restrict__ rec_out,
    unsigned char* __restrict__ dl8_out, int E)
{
    __shared__ int4 stA[CHUNK];                 // 32KB unsorted records
    __shared__ unsigned short rank16[CHUNK];    // 4KB chunk-bucket rank
    __shared__ unsigned short inv16[CHUNK];     // 4KB sortedpos -> unsorted j
    __shared__ int cnt[NBMAX];                  // 2KB
    __shared__ int start[NBMAX];                // 2KB
    __shared__ int gpos[NBMAX];                 // 2KB
    __shared__ float Wes[64];

    const int tid = threadIdx.x;
    if (tid < 64) Wes[tid] = We[tid];
    for (int i = tid; i < NBMAX; i += 256) cnt[i] = 0;
    __syncthreads();

    const int e0 = blockIdx.x * CHUNK;
    const int ce = min(CHUNK, E - e0);

    // phase 1: compute records + chunk-local bucket ranks
    for (int j = tid; j < ce; j += 256) {
        int e = e0 + j;
        int d = dst[e];
        int s = src[e];
        float4 as4 = *(const float4*)(a_src + (size_t)s * 4);   // L2/L3-resident
        const float4* ea4 = (const float4*)(ea + (size_t)e * 16);
        float4 q0 = ea4[0], q1 = ea4[1], q2 = ea4[2], q3 = ea4[3];
        float eav[16] = {q0.x, q0.y, q0.z, q0.w, q1.x, q1.y, q1.z, q1.w,
                         q2.x, q2.y, q2.z, q2.w, q3.x, q3.y, q3.z, q3.w};
        float esc[4] = {0.f, 0.f, 0.f, 0.f};
        #pragma unroll
        for (int k = 0; k < 16; ++k) {
            #pragma unroll
            for (int hh = 0; hh < 4; ++hh) esc[hh] += eav[k] * Wes[k * 4 + hh];
        }
        __half2 p01 = __floats2half2_rn(as4.x + esc[0], as4.y + esc[1]);
        __half2 p23 = __floats2half2_rn(as4.z + esc[2], as4.w + esc[3]);
        int y = *reinterpret_cast<int*>(&p01);
        int z = *reinterpret_cast<int*>(&p23);
        stA[j] = make_int4(s, y, z, d);
        rank16[j] = (unsigned short)atomicAdd(&cnt[((unsigned)d) >> BSH], 1);
    }
    __syncthreads();

    // phase 2: exclusive scan cnt -> start (wave 0)
    if (tid < 64) {
        int c[8]; int s = 0;
        #pragma unroll
        for (int j = 0; j < 8; ++j) { c[j] = cnt[tid * 8 + j]; s += c[j]; }
        int incl = s;
        #pragma unroll
        for (int off = 1; off < 64; off <<= 1) {
            int u = __shfl_up(incl, off, 64);
            if (tid >= off) incl += u;
        }
        int run = incl - s;
        #pragma unroll
        for (int j = 0; j < 8; ++j) { start[tid * 8 + j] = run; run += c[j]; }
    }
    __syncthreads();

    // phase 3: reserve global segments (one atomic per non-empty bucket)
    for (int b = tid; b < NBMAX; b += 256)
        if (cnt[b] > 0) gpos[b] = atomicAdd(&bcur[b * PAD], cnt[b]);
    __syncthreads();

    // phase 4: build inverse permutation (sorted pos -> unsorted j)
    for (int j = tid; j < ce; j += 256) {
        int b = ((unsigned)stA[j].w) >> BSH;
        inv16[start[b] + rank16[j]] = (unsigned short)j;
    }
    __syncthreads();

    // phase 5: flush in sorted order -> contiguous global runs
    for (int p = tid; p < ce; p += 256) {
        int4 r = stA[inv16[p]];
        int b = ((unsigned)r.w) >> BSH;
        int g = gpos[b] + (p - start[b]);
        rec_out[g] = r;
        dl8_out[g] = (unsigned char)(r.w & 255);
    }
}

// ---------------------------------------------------------------------------
// Kernel 5: bucket-local aggregation + residual + LayerNorm.
// 8 sibling blocks per bucket, each owns 32 nodes. Phase A: bin edge indices
// from the 1B dl8 stream into idx16[32][64]. Phase B: wave-per-node; records
// fetched via uniform 16B loads from the L2-hot bucket region (no shuffles).
// ---------------------------------------------------------------------------
__global__ __launch_bounds__(256) void k_agg(
    const int* __restrict__ bstart, const int* __restrict__ bcount,
    const int4* __restrict__ recs, const unsigned char* __restrict__ dl8,
    const __half* __restrict__ h16, const float* __restrict__ a_dst,
    const float* __restrict__ gamma, const float* __restrict__ beta,
    float* __restrict__ out, int n)
{
    const int b    = blockIdx.x >> 3;
    const int sub  = blockIdx.x & 7;
    const int tid  = threadIdx.x;
    const int lane = tid & 63;
    const int wv   = tid >> 6;
    const int nbase = (b << BSH) + sub * 32;
    if (nbase >= n) return;

    __shared__ unsigned short idx16[32 * 64];   // 4KB
    __shared__ int cur[32];
    if (tid < 32) cur[tid] = 0;
    __syncthreads();

    const int base = bstart[b];
    const int bcnt = bcount[b];
    const int dlo  = sub * 32;
    for (int i = tid; i < bcnt; i += 256) {
        int dl = (int)dl8[base + i] - dlo;
        if ((unsigned)dl < 32u) {
            int r = atomicAdd(&cur[dl], 1);
            if (r < 64) idx16[dl * 64 + r] = (unsigned short)i;
        }
    }
    __syncthreads();

    const int hh   = lane >> 4;
    const int hilo = hh & 1;

#define PROC_EDGE(HV, YW, ZW)                                            \
    {                                                                    \
        int w_ = (hh < 2) ? (YW) : (ZW);                                 \
        float2 f2_ = __half22float2(*reinterpret_cast<__half2*>(&w_));   \
        float a_ = (hilo ? f2_.y : f2_.x) + ad;                          \
        a_ = (a_ >= 0.f) ? a_ : NEG_SLOPE * a_;                          \
        float w2_ = __expf(a_);                                          \
        sum  += w2_;                                                     \
        accv += w2_ * (HV);                                              \
    }

    for (int dl = wv; dl < 32; dl += 4) {
        int node = nbase + dl;
        if (node >= n) continue;
        int deg = min(cur[dl], 64);
        float h_node = __half2float(h16[(size_t)node * 64 + lane]);
        float ad = a_dst[(size_t)node * 4 + hh];
        float sum = 0.f, accv = 0.f;

        int k = 0;
        for (; k + 8 <= deg; k += 8) {
            int4 rc[8]; float hv[8];
            #pragma unroll
            for (int t = 0; t < 8; ++t)
                rc[t] = recs[(size_t)base + idx16[dl * 64 + k + t]];
            #pragma unroll
            for (int t = 0; t < 8; ++t)
                hv[t] = __half2float(h16[(size_t)rc[t].x * 64 + lane]);
            #pragma unroll
            for (int t = 0; t < 8; ++t) PROC_EDGE(hv[t], rc[t].y, rc[t].z);
        }
        for (; k < deg; ++k) {
            int4 rc = recs[(size_t)base + idx16[dl * 64 + k]];
            float hv = __half2float(h16[(size_t)rc.x * 64 + lane]);
            PROC_EDGE(hv, rc.y, rc.z);
        }

        float y = accv / (sum + EPS_SM) + h_node;

        float t1 = y;
        #pragma unroll
        for (int off = 32; off; off >>= 1) t1 += __shfl_xor(t1, off, 64);
        float mu = t1 * (1.f / 64.f);
        float dv = y - mu;
        float vs = dv * dv;
        #pragma unroll
        for (int off = 32; off; off >>= 1) vs += __shfl_xor(vs, off, 64);
        float var = vs * (1.f / 64.f);
        out[(size_t)node * 64 + lane] =
            dv * rsqrtf(var + EPS_LN) * gamma[lane] + beta[lane];
    }
#undef PROC_EDGE
}

// ---------------------------------------------------------------------------
extern "C" void kernel_launch(void* const* d_in, const int* in_sizes, int n_in,
                              void* d_out, int out_size, void* d_ws, size_t ws_size,
                              hipStream_t stream)
{
    const float* x     = (const float*)d_in[0];
    const int*   ei    = (const int*)  d_in[1];
    const float* ea    = (const float*)d_in[2];
    const float* Wn    = (const float*)d_in[3];
    const float* We    = (const float*)d_in[4];
    const float* asrcW = (const float*)d_in[5];
    const float* adstW = (const float*)d_in[6];
    const float* gamma = (const float*)d_in[7];
    const float* beta  = (const float*)d_in[8];
    float* out = (float*)d_out;

    const int n = in_sizes[0] / 64;
    const int E = in_sizes[1] / 2;
    const int* src = ei;
    const int* dst = ei + E;
    const int NB = (n + 255) >> BSH;        // buckets (<= NBMAX)
    const int nchunk = (E + CHUNK - 1) / CHUNK;

    float* ws = (float*)d_ws;
    size_t off = 0;
    __half* h16  = (__half*)(ws + off); off += (size_t)n * 32;   // n*64 halves
    float* a_src = ws + off; off += (size_t)n * 4;
    float* a_dst = ws + off; off += (size_t)n * 4;
    int4* recs   = (int4*)(ws + off); off += (size_t)E * 4;
    unsigned char* dl8 = (unsigned char*)(ws + off); off += ((size_t)E + 3) / 4;
    int* ibase  = (int*)(ws + off);
    int* gbcnt  = ibase;                       // NBMAX*PAD
    int* bcur   = ibase + NBMAX * PAD;         // NBMAX*PAD
    int* bstart = ibase + 2 * NBMAX * PAD;     // NBMAX
    int* bcount = bstart + NBMAX;              // NBMAX

    hipMemsetAsync(gbcnt, 0, (size_t)NBMAX * PAD * sizeof(int), stream);

    k_node<<<(n + 63) / 64, 256, 0, stream>>>(x, Wn, asrcW, adstW, h16, a_src, a_dst, n);
    k_bhist<<<nchunk, 256, 0, stream>>>(dst, gbcnt, E);
    k_bscan<<<1, 64, 0, stream>>>(gbcnt, bstart, bcount, bcur);
    k_pass1<<<nchunk, 256, 0, stream>>>(src, dst, ea, We, a_src, bcur, recs, dl8, E);
    k_agg<<<NB * 8, 256, 0, stream>>>(bstart, bcount, recs, dl8, h16, a_dst,
                                      gamma, beta, out, n);
}

// Round 10
// 223.035 us; speedup vs baseline: 1.4851x; 1.1256x over previous
//
#include <hip/hip_runtime.h>
#include <hip/hip_fp16.h>
#include <math.h>

#define NEG_SLOPE 0.2f
#define EPS_SM 1e-8f
#define EPS_LN 1e-5f
#define PAD 16          // one global counter per 64B line
#define BSH 8           // bucket = dst >> 8  (256 nodes/bucket)
#define NBMAX 512       // max buckets (n <= 131072)
#define CHUNK 2048      // edges per pass1/bhist block

// ---------------------------------------------------------------------------
// Kernel 1: h = x @ W_node (64x64) + fused a_src/a_dst projections.
// 64 rows per 256-thread block, register-tiled 4x4 per thread. h stored f16.
// ---------------------------------------------------------------------------
__global__ __launch_bounds__(256) void k_node(
    const float* __restrict__ x, const float* __restrict__ Wn,
    const float* __restrict__ attn_src, const float* __restrict__ attn_dst,
    __half* __restrict__ h16, float* __restrict__ a_src, float* __restrict__ a_dst,
    int n)
{
    __shared__ float Ws[64][64];   // W[k][col]
    __shared__ float xs[64][64];   // x[r][k]
    const int tid  = threadIdx.x;
    const int row0 = blockIdx.x * 64;

    const float4* Wn4 = (const float4*)Wn;
    #pragma unroll
    for (int i = tid; i < 1024; i += 256) {
        float4 v = Wn4[i];
        *(float4*)&Ws[i >> 4][(i & 15) * 4] = v;
    }
    const float4* x4 = (const float4*)x;
    #pragma unroll
    for (int i = tid; i < 1024; i += 256) {
        int r  = i >> 4;
        int gr = row0 + r;
        float4 v = (gr < n) ? x4[(size_t)gr * 16 + (i & 15)]
                            : make_float4(0.f, 0.f, 0.f, 0.f);
        *(float4*)&xs[r][(i & 15) * 4] = v;
    }
    __syncthreads();

    const int c4 = tid & 15;
    const int r4 = tid >> 4;

    float4 acc0 = make_float4(0.f, 0.f, 0.f, 0.f);
    float4 acc1 = make_float4(0.f, 0.f, 0.f, 0.f);
    float4 acc2 = make_float4(0.f, 0.f, 0.f, 0.f);
    float4 acc3 = make_float4(0.f, 0.f, 0.f, 0.f);

    #pragma unroll 8
    for (int k = 0; k < 64; ++k) {
        float4 w = *(const float4*)&Ws[k][c4 * 4];
        float x0 = xs[r4     ][k];
        float x1 = xs[r4 + 16][k];
        float x2 = xs[r4 + 32][k];
        float x3 = xs[r4 + 48][k];
        acc0.x += x0 * w.x; acc0.y += x0 * w.y; acc0.z += x0 * w.z; acc0.w += x0 * w.w;
        acc1.x += x1 * w.x; acc1.y += x1 * w.y; acc1.z += x1 * w.z; acc1.w += x1 * w.w;
        acc2.x += x2 * w.x; acc2.y += x2 * w.y; acc2.z += x2 * w.z; acc2.w += x2 * w.w;
        acc3.x += x3 * w.x; acc3.y += x3 * w.y; acc3.z += x3 * w.z; acc3.w += x3 * w.w;
    }

    const float4 asw = *(const float4*)&attn_src[c4 * 4];
    const float4 adw = *(const float4*)&attn_dst[c4 * 4];
    const int hh = c4 >> 2;
    const bool writer = (c4 & 3) == 0;

    float4 accs[4] = {acc0, acc1, acc2, acc3};
    #pragma unroll
    for (int j = 0; j < 4; ++j) {
        int gr = row0 + r4 + 16 * j;
        if (gr < n) {
            __half2 p0 = __floats2half2_rn(accs[j].x, accs[j].y);
            __half2 p1 = __floats2half2_rn(accs[j].z, accs[j].w);
            uint2 pk = make_uint2(*reinterpret_cast<unsigned*>(&p0),
                                  *reinterpret_cast<unsigned*>(&p1));
            *(uint2*)&h16[(size_t)gr * 64 + c4 * 4] = pk;
            float ps = accs[j].x * asw.x + accs[j].y * asw.y +
                       accs[j].z * asw.z + accs[j].w * asw.w;
            float pd = accs[j].x * adw.x + accs[j].y * adw.y +
                       accs[j].z * adw.z + accs[j].w * adw.w;
            ps += __shfl_xor(ps, 1, 64); ps += __shfl_xor(ps, 2, 64);
            pd += __shfl_xor(pd, 1, 64); pd += __shfl_xor(pd, 2, 64);
            if (writer) {
                a_src[(size_t)gr * 4 + hh] = ps;
                a_dst[(size_t)gr * 4 + hh] = pd;
            }
        } else {
            float ps = 0.f, pd = 0.f;
            ps += __shfl_xor(ps, 1, 64); ps += __shfl_xor(ps, 2, 64);
            pd += __shfl_xor(pd, 1, 64); pd += __shfl_xor(pd, 2, 64);
        }
    }
}

// ---------------------------------------------------------------------------
// Kernel 2: bucket histogram (LDS-staged, one global add per (chunk,bucket)).
// ---------------------------------------------------------------------------
__global__ __launch_bounds__(256) void k_bhist(
    const int* __restrict__ dst, int* __restrict__ gbcnt, int E)
{
    __shared__ int cnt[NBMAX];
    const int tid = threadIdx.x;
    for (int i = tid; i < NBMAX; i += 256) cnt[i] = 0;
    __syncthreads();
    const int e0 = blockIdx.x * CHUNK;
    const int ce = min(CHUNK, E - e0);
    for (int j = tid; j < ce; j += 256)
        atomicAdd(&cnt[((unsigned)dst[e0 + j]) >> BSH], 1);
    __syncthreads();
    for (int b = tid; b < NBMAX; b += 256)
        if (cnt[b] > 0) atomicAdd(&gbcnt[b * PAD], cnt[b]);
}

// ---------------------------------------------------------------------------
// Kernel 3: exclusive scan of 512 bucket counts (one wave).
// ---------------------------------------------------------------------------
__global__ void k_bscan(const int* __restrict__ gbcnt,
                        int* __restrict__ bstart, int* __restrict__ bcount,
                        int* __restrict__ bcur)
{
    int lane = threadIdx.x;   // 64 threads
    int c[8]; int s = 0;
    #pragma unroll
    for (int j = 0; j < 8; ++j) { c[j] = gbcnt[(lane * 8 + j) * PAD]; s += c[j]; }
    int incl = s;
    #pragma unroll
    for (int off = 1; off < 64; off <<= 1) {
        int u = __shfl_up(incl, off, 64);
        if (lane >= off) incl += u;
    }
    int run = incl - s;
    #pragma unroll
    for (int j = 0; j < 8; ++j) {
        int b = lane * 8 + j;
        bstart[b] = run;
        bcount[b] = c[j];
        bcur[b * PAD] = run;
        run += c[j];
    }
}

// ---------------------------------------------------------------------------
// Kernel 4: bucket-grouped scatter, register-resident (no LDS record staging).
// Per 2048-edge chunk: 8 edges/thread; LDS-rank per (chunk,bucket); one global
// atomic per non-empty bucket reserves a contiguous run; records written
// directly from registers to gpos[b]+rank (line-dense within the run).
// Record: int4 { src, f16x2(as01+esc01), f16x2(as23+esc23), dst }.
// ---------------------------------------------------------------------------
__global__ __launch_bounds__(256) void k_pass1(
    const int* __restrict__ src, const int* __restrict__ dst,
    const float* __restrict__ ea, const float* __restrict__ We,
    const float* __restrict__ a_src,
    int* __restrict__ bcur, int4* __restrict__ rec_out,
    unsigned char* __restrict__ dl8_out, int E)
{
    __shared__ float Wes[64];       // W_edge [16][4]
    __shared__ int cnt[NBMAX];      // 2KB
    __shared__ int gpos[NBMAX];     // 2KB
    const int tid = threadIdx.x;
    if (tid < 64) Wes[tid] = We[tid];
    for (int i = tid; i < NBMAX; i += 256) cnt[i] = 0;
    __syncthreads();

    const int e0 = blockIdx.x * CHUNK;
    int d[8], s[8], rk[8];
    #pragma unroll
    for (int j = 0; j < 8; ++j) {
        int e = e0 + j * 256 + tid;
        bool v = e < E;
        d[j] = v ? dst[e] : -1;
        s[j] = v ? src[e] : 0;
    }
    #pragma unroll
    for (int j = 0; j < 8; ++j)
        rk[j] = (d[j] >= 0) ? atomicAdd(&cnt[((unsigned)d[j]) >> BSH], 1) : 0;
    __syncthreads();

    for (int b = tid; b < NBMAX; b += 256)
        if (cnt[b] > 0) gpos[b] = atomicAdd(&bcur[b * PAD], cnt[b]);
    __syncthreads();

    // a_src gathers for all 8 edges issued up-front (L2/L3-resident)
    float4 as4[8];
    #pragma unroll
    for (int j = 0; j < 8; ++j)
        as4[j] = (d[j] >= 0) ? *(const float4*)(a_src + (size_t)s[j] * 4)
                             : make_float4(0.f, 0.f, 0.f, 0.f);

    #pragma unroll
    for (int j = 0; j < 8; ++j) {
        if (d[j] < 0) continue;
        int e = e0 + j * 256 + tid;
        const float4* ea4 = (const float4*)(ea + (size_t)e * 16);
        float4 q0 = ea4[0], q1 = ea4[1], q2 = ea4[2], q3 = ea4[3];
        float eav[16] = {q0.x, q0.y, q0.z, q0.w, q1.x, q1.y, q1.z, q1.w,
                         q2.x, q2.y, q2.z, q2.w, q3.x, q3.y, q3.z, q3.w};
        float esc[4] = {0.f, 0.f, 0.f, 0.f};
        #pragma unroll
        for (int k = 0; k < 16; ++k) {
            #pragma unroll
            for (int hh = 0; hh < 4; ++hh) esc[hh] += eav[k] * Wes[k * 4 + hh];
        }
        __half2 p01 = __floats2half2_rn(as4[j].x + esc[0], as4[j].y + esc[1]);
        __half2 p23 = __floats2half2_rn(as4[j].z + esc[2], as4[j].w + esc[3]);
        int y = *reinterpret_cast<int*>(&p01);
        int z = *reinterpret_cast<int*>(&p23);
        int g = gpos[((unsigned)d[j]) >> BSH] + rk[j];
        rec_out[g] = make_int4(s[j], y, z, d[j]);
        dl8_out[g] = (unsigned char)(d[j] & 255);
    }
}

// ---------------------------------------------------------------------------
// Kernel 5: per-bucket counting sort to per-node-contiguous order (ONCE per
// bucket, 1024 threads). Emits recs2 (node-grouped) + nstart/ndeg arrays.
// All record traffic is L2/L3-hot (just written by pass1).
// ---------------------------------------------------------------------------
__global__ __launch_bounds__(1024) void k_bin(
    const int* __restrict__ bstart, const int* __restrict__ bcount,
    const int4* __restrict__ recs, const unsigned char* __restrict__ dl8,
    int4* __restrict__ recs2, int* __restrict__ nstart, int* __restrict__ ndeg,
    int n)
{
    __shared__ int cnt[256], st[256], cur[256];
    const int b    = blockIdx.x;
    const int tid  = threadIdx.x;
    const int nbase = b << BSH;
    const int base = bstart[b];
    const int bcnt = bcount[b];

    if (tid < 256) cnt[tid] = 0;
    __syncthreads();

    for (int i = tid; i < bcnt; i += 1024)
        atomicAdd(&cnt[dl8[base + i]], 1);
    __syncthreads();

    if (tid < 64) {
        int c0 = cnt[4 * tid], c1 = cnt[4 * tid + 1];
        int c2 = cnt[4 * tid + 2], c3 = cnt[4 * tid + 3];
        int s = c0 + c1 + c2 + c3;
        int incl = s;
        #pragma unroll
        for (int off = 1; off < 64; off <<= 1) {
            int u = __shfl_up(incl, off, 64);
            if (tid >= off) incl += u;
        }
        int run = incl - s;
        st[4 * tid    ] = run; cur[4 * tid    ] = run; run += c0;
        st[4 * tid + 1] = run; cur[4 * tid + 1] = run; run += c1;
        st[4 * tid + 2] = run; cur[4 * tid + 2] = run; run += c2;
        st[4 * tid + 3] = run; cur[4 * tid + 3] = run;
    }
    __syncthreads();

    if (tid < 256) {
        int node = nbase + tid;
        if (node < n) {
            nstart[node] = base + st[tid];
            ndeg[node]   = cnt[tid];
        }
    }

    for (int i = tid; i < bcnt; i += 1024) {
        int4 r = recs[base + i];
        int p = atomicAdd(&cur[r.w & 255], 1);
        recs2[base + p] = r;
    }
}

// ---------------------------------------------------------------------------
// Kernel 6: wave-per-node aggregation + residual + LayerNorm.
// Records are per-node contiguous: lane-coalesced loads + shfl broadcast.
// No LDS, no binning. 8 h-row gathers in flight.
// ---------------------------------------------------------------------------
__global__ __launch_bounds__(256) void k_agg(
    const int* __restrict__ nstart, const int* __restrict__ ndeg,
    const int4* __restrict__ recs2, const __half* __restrict__ h16,
    const float* __restrict__ a_dst,
    const float* __restrict__ gamma, const float* __restrict__ beta,
    float* __restrict__ out, int n)
{
    int gid  = blockIdx.x * 256 + threadIdx.x;
    int node = gid >> 6;
    int lane = gid & 63;
    if (node >= n) return;
    const int hh   = lane >> 4;
    const int hilo = hh & 1;

    const int rs  = nstart[node];
    const int deg = ndeg[node];

    const float h_node = __half2float(h16[(size_t)node * 64 + lane]);
    float4 ad4 = *(const float4*)(a_dst + (size_t)node * 4);
    const float ad = (hh == 0) ? ad4.x : (hh == 1) ? ad4.y : (hh == 2) ? ad4.z : ad4.w;

    float sum = 0.f, accv = 0.f;

#define PROC_EDGE(HV, YW, ZW)                                            \
    {                                                                    \
        int w_ = (hh < 2) ? (YW) : (ZW);                                 \
        float2 f2_ = __half22float2(*reinterpret_cast<__half2*>(&w_));   \
        float a_ = (hilo ? f2_.y : f2_.x) + ad;                          \
        a_ = (a_ >= 0.f) ? a_ : NEG_SLOPE * a_;                          \
        float w2_ = __expf(a_);                                          \
        sum  += w2_;                                                     \
        accv += w2_ * (HV);                                              \
    }

    for (int b0 = 0; b0 < deg; b0 += 64) {
        int cnt = min(64, deg - b0);
        int4 myc = (b0 + lane < deg) ? recs2[(size_t)rs + b0 + lane]
                                     : make_int4(0, 0, 0, 0);
        int i = 0;
        for (; i + 8 <= cnt; i += 8) {
            int sj[8], yj[8], zj[8];
            float hv[8];
            #pragma unroll
            for (int j = 0; j < 8; ++j) {
                sj[j] = __shfl(myc.x, i + j, 64);
                yj[j] = __shfl(myc.y, i + j, 64);
                zj[j] = __shfl(myc.z, i + j, 64);
            }
            #pragma unroll
            for (int j = 0; j < 8; ++j)
                hv[j] = __half2float(h16[(size_t)sj[j] * 64 + lane]);
            #pragma unroll
            for (int j = 0; j < 8; ++j) PROC_EDGE(hv[j], yj[j], zj[j]);
        }
        for (; i < cnt; ++i) {
            int s0 = __shfl(myc.x, i, 64);
            int y0 = __shfl(myc.y, i, 64);
            int z0 = __shfl(myc.z, i, 64);
            float hv0 = __half2float(h16[(size_t)s0 * 64 + lane]);
            PROC_EDGE(hv0, y0, z0);
        }
    }
#undef PROC_EDGE

    float y = accv / (sum + EPS_SM) + h_node;

    float t1 = y;
    #pragma unroll
    for (int off = 32; off; off >>= 1) t1 += __shfl_xor(t1, off, 64);
    float mu = t1 * (1.f / 64.f);
    float dv = y - mu;
    float vs = dv * dv;
    #pragma unroll
    for (int off = 32; off; off >>= 1) vs += __shfl_xor(vs, off, 64);
    float var = vs * (1.f / 64.f);
    out[(size_t)node * 64 + lane] = dv * rsqrtf(var + EPS_LN) * gamma[lane] + beta[lane];
}

// ---------------------------------------------------------------------------
extern "C" void kernel_launch(void* const* d_in, const int* in_sizes, int n_in,
                              void* d_out, int out_size, void* d_ws, size_t ws_size,
                              hipStream_t stream)
{
    const float* x     = (const float*)d_in[0];
    const int*   ei    = (const int*)  d_in[1];
    const float* ea    = (const float*)d_in[2];
    const float* Wn    = (const float*)d_in[3];
    const float* We    = (const float*)d_in[4];
    const float* asrcW = (const float*)d_in[5];
    const float* adstW = (const float*)d_in[6];
    const float* gamma = (const float*)d_in[7];
    const float* beta  = (const float*)d_in[8];
    float* out = (float*)d_out;

    const int n = in_sizes[0] / 64;
    const int E = in_sizes[1] / 2;
    const int* src = ei;
    const int* dst = ei + E;
    const int NB = (n + 255) >> BSH;
    const int nchunk = (E + CHUNK - 1) / CHUNK;

    float* ws = (float*)d_ws;
    size_t off = 0;
    __half* h16  = (__half*)(ws + off); off += (size_t)n * 32;   // n*64 halves
    float* a_src = ws + off; off += (size_t)n * 4;
    float* a_dst = ws + off; off += (size_t)n * 4;
    int4* recs   = (int4*)(ws + off); off += (size_t)E * 4;
    int4* recs2  = (int4*)(ws + off); off += (size_t)E * 4;
    unsigned char* dl8 = (unsigned char*)(ws + off); off += ((size_t)E + 3) / 4;
    int* ibase  = (int*)(ws + off);
    int* gbcnt  = ibase;                       // NBMAX*PAD
    int* bcur   = ibase + NBMAX * PAD;         // NBMAX*PAD
    int* bstart = ibase + 2 * NBMAX * PAD;     // NBMAX
    int* bcount = bstart + NBMAX;              // NBMAX
    int* nstart = bcount + NBMAX;              // n
    int* ndeg   = nstart + n;                  // n

    hipMemsetAsync(gbcnt, 0, (size_t)NBMAX * PAD * sizeof(int), stream);

    k_node<<<(n + 63) / 64, 256, 0, stream>>>(x, Wn, asrcW, adstW, h16, a_src, a_dst, n);
    k_bhist<<<nchunk, 256, 0, stream>>>(dst, gbcnt, E);
    k_bscan<<<1, 64, 0, stream>>>(gbcnt, bstart, bcount, bcur);
    k_pass1<<<nchunk, 256, 0, stream>>>(src, dst, ea, We, a_src, bcur, recs, dl8, E);
    k_bin<<<NB, 1024, 0, stream>>>(bstart, bcount, recs, dl8, recs2, nstart, ndeg, n);
    k_agg<<<((size_t)n * 64 + 255) / 256, 256, 0, stream>>>(
        nstart, ndeg, recs2, h16, a_dst, gamma, beta, out, n);
}

// Round 11
// 198.815 us; speedup vs baseline: 1.6660x; 1.1218x over previous
//
#include <hip/hip_runtime.h>
#include <hip/hip_fp16.h>
#include <math.h>

#define NEG_SLOPE 0.2f
#define EPS_SM 1e-8f
#define EPS_LN 1e-5f
#define PAD 16          // one global counter per 64B line
#define BSH 8           // bucket = dst >> 8  (256 nodes/bucket)
#define NBMAX 512       // max buckets (n <= 131072)
#define CHUNK 2048      // edges per pass1/bhist block

// ---------------------------------------------------------------------------
// Kernel 1: h = x @ W_node (64x64) + fused a_src/a_dst projections.
// 64 rows per 256-thread block, register-tiled 4x4 per thread. h stored f16.
// ---------------------------------------------------------------------------
__global__ __launch_bounds__(256) void k_node(
    const float* __restrict__ x, const float* __restrict__ Wn,
    const float* __restrict__ attn_src, const float* __restrict__ attn_dst,
    __half* __restrict__ h16, float* __restrict__ a_src, float* __restrict__ a_dst,
    int n)
{
    __shared__ float Ws[64][64];   // W[k][col]
    __shared__ float xs[64][64];   // x[r][k]
    const int tid  = threadIdx.x;
    const int row0 = blockIdx.x * 64;

    const float4* Wn4 = (const float4*)Wn;
    #pragma unroll
    for (int i = tid; i < 1024; i += 256) {
        float4 v = Wn4[i];
        *(float4*)&Ws[i >> 4][(i & 15) * 4] = v;
    }
    const float4* x4 = (const float4*)x;
    #pragma unroll
    for (int i = tid; i < 1024; i += 256) {
        int r  = i >> 4;
        int gr = row0 + r;
        float4 v = (gr < n) ? x4[(size_t)gr * 16 + (i & 15)]
                            : make_float4(0.f, 0.f, 0.f, 0.f);
        *(float4*)&xs[r][(i & 15) * 4] = v;
    }
    __syncthreads();

    const int c4 = tid & 15;
    const int r4 = tid >> 4;

    float4 acc0 = make_float4(0.f, 0.f, 0.f, 0.f);
    float4 acc1 = make_float4(0.f, 0.f, 0.f, 0.f);
    float4 acc2 = make_float4(0.f, 0.f, 0.f, 0.f);
    float4 acc3 = make_float4(0.f, 0.f, 0.f, 0.f);

    #pragma unroll 8
    for (int k = 0; k < 64; ++k) {
        float4 w = *(const float4*)&Ws[k][c4 * 4];
        float x0 = xs[r4     ][k];
        float x1 = xs[r4 + 16][k];
        float x2 = xs[r4 + 32][k];
        float x3 = xs[r4 + 48][k];
        acc0.x += x0 * w.x; acc0.y += x0 * w.y; acc0.z += x0 * w.z; acc0.w += x0 * w.w;
        acc1.x += x1 * w.x; acc1.y += x1 * w.y; acc1.z += x1 * w.z; acc1.w += x1 * w.w;
        acc2.x += x2 * w.x; acc2.y += x2 * w.y; acc2.z += x2 * w.z; acc2.w += x2 * w.w;
        acc3.x += x3 * w.x; acc3.y += x3 * w.y; acc3.z += x3 * w.z; acc3.w += x3 * w.w;
    }

    const float4 asw = *(const float4*)&attn_src[c4 * 4];
    const float4 adw = *(const float4*)&attn_dst[c4 * 4];
    const int hh = c4 >> 2;
    const bool writer = (c4 & 3) == 0;

    float4 accs[4] = {acc0, acc1, acc2, acc3};
    #pragma unroll
    for (int j = 0; j < 4; ++j) {
        int gr = row0 + r4 + 16 * j;
        if (gr < n) {
            __half2 p0 = __floats2half2_rn(accs[j].x, accs[j].y);
            __half2 p1 = __floats2half2_rn(accs[j].z, accs[j].w);
            uint2 pk = make_uint2(*reinterpret_cast<unsigned*>(&p0),
                                  *reinterpret_cast<unsigned*>(&p1));
            *(uint2*)&h16[(size_t)gr * 64 + c4 * 4] = pk;
            float ps = accs[j].x * asw.x + accs[j].y * asw.y +
                       accs[j].z * asw.z + accs[j].w * asw.w;
            float pd = accs[j].x * adw.x + accs[j].y * adw.y +
                       accs[j].z * adw.z + accs[j].w * adw.w;
            ps += __shfl_xor(ps, 1, 64); ps += __shfl_xor(ps, 2, 64);
            pd += __shfl_xor(pd, 1, 64); pd += __shfl_xor(pd, 2, 64);
            if (writer) {
                a_src[(size_t)gr * 4 + hh] = ps;
                a_dst[(size_t)gr * 4 + hh] = pd;
            }
        } else {
            float ps = 0.f, pd = 0.f;
            ps += __shfl_xor(ps, 1, 64); ps += __shfl_xor(ps, 2, 64);
            pd += __shfl_xor(pd, 1, 64); pd += __shfl_xor(pd, 2, 64);
        }
    }
}

// ---------------------------------------------------------------------------
// Kernel 2: bucket histogram (LDS-staged, one global add per (chunk,bucket)).
// ---------------------------------------------------------------------------
__global__ __launch_bounds__(256) void k_bhist(
    const int* __restrict__ dst, int* __restrict__ gbcnt, int E)
{
    __shared__ int cnt[NBMAX];
    const int tid = threadIdx.x;
    for (int i = tid; i < NBMAX; i += 256) cnt[i] = 0;
    __syncthreads();
    const int e0 = blockIdx.x * CHUNK;
    const int ce = min(CHUNK, E - e0);
    for (int j = tid; j < ce; j += 256)
        atomicAdd(&cnt[((unsigned)dst[e0 + j]) >> BSH], 1);
    __syncthreads();
    for (int b = tid; b < NBMAX; b += 256)
        if (cnt[b] > 0) atomicAdd(&gbcnt[b * PAD], cnt[b]);
}

// ---------------------------------------------------------------------------
// Kernel 3: exclusive scan of 512 bucket counts (one wave).
// ---------------------------------------------------------------------------
__global__ void k_bscan(const int* __restrict__ gbcnt,
                        int* __restrict__ bstart, int* __restrict__ bcount,
                        int* __restrict__ bcur)
{
    int lane = threadIdx.x;   // 64 threads
    int c[8]; int s = 0;
    #pragma unroll
    for (int j = 0; j < 8; ++j) { c[j] = gbcnt[(lane * 8 + j) * PAD]; s += c[j]; }
    int incl = s;
    #pragma unroll
    for (int off = 1; off < 64; off <<= 1) {
        int u = __shfl_up(incl, off, 64);
        if (lane >= off) incl += u;
    }
    int run = incl - s;
    #pragma unroll
    for (int j = 0; j < 8; ++j) {
        int b = lane * 8 + j;
        bstart[b] = run;
        bcount[b] = c[j];
        bcur[b * PAD] = run;
        run += c[j];
    }
}

// ---------------------------------------------------------------------------
// Kernel 4: bucket-grouped scatter. 512 threads, 4 edges/thread.
// All long-latency memory (a_src gathers, ea streams) issued and consumed
// BEFORE the first barrier; ranking overlaps the loads. Then one global
// atomic per non-empty bucket reserves a contiguous run; records written
// from registers to gpos[b]+rank (line-dense within the run).
// Record: int4 { src, f16x2(as01+esc01), f16x2(as23+esc23), dst }.
// ---------------------------------------------------------------------------
__global__ __launch_bounds__(512) void k_pass1(
    const int* __restrict__ src, const int* __restrict__ dst,
    const float* __restrict__ ea, const float* __restrict__ We,
    const float* __restrict__ a_src,
    int* __restrict__ bcur, int4* __restrict__ rec_out,
    unsigned char* __restrict__ dl8_out, int E)
{
    __shared__ float Wes[64];       // W_edge [16][4]
    __shared__ int cnt[NBMAX];      // 2KB
    __shared__ int gpos[NBMAX];     // 2KB
    const int tid = threadIdx.x;
    if (tid < 64) Wes[tid] = We[tid];
    for (int i = tid; i < NBMAX; i += 512) cnt[i] = 0;
    __syncthreads();

    const int e0 = blockIdx.x * CHUNK;
    int d[4], s[4], rk[4];
    #pragma unroll
    for (int j = 0; j < 4; ++j) {
        int e = e0 + j * 512 + tid;
        bool v = e < E;
        d[j] = v ? dst[e] : -1;
        s[j] = v ? src[e] : 0;
    }

    // rank via LDS atomics (overlaps the gathers issued just below
    // from other waves' perspective; no barrier until records are built)
    #pragma unroll
    for (int j = 0; j < 4; ++j)
        rk[j] = (d[j] >= 0) ? atomicAdd(&cnt[((unsigned)d[j]) >> BSH], 1) : 0;

    // a_src gathers for all 4 edges issued up-front (L2/L3-resident)
    float4 as4[4];
    #pragma unroll
    for (int j = 0; j < 4; ++j)
        as4[j] = (d[j] >= 0) ? *(const float4*)(a_src + (size_t)s[j] * 4)
                             : make_float4(0.f, 0.f, 0.f, 0.f);

    // stream ea and build records in registers
    int ry[4], rz[4];
    #pragma unroll
    for (int j = 0; j < 4; ++j) {
        if (d[j] < 0) { ry[j] = 0; rz[j] = 0; continue; }
        int e = e0 + j * 512 + tid;
        const float4* ea4 = (const float4*)(ea + (size_t)e * 16);
        float4 q0 = ea4[0], q1 = ea4[1], q2 = ea4[2], q3 = ea4[3];
        float eav[16] = {q0.x, q0.y, q0.z, q0.w, q1.x, q1.y, q1.z, q1.w,
                         q2.x, q2.y, q2.z, q2.w, q3.x, q3.y, q3.z, q3.w};
        float esc[4] = {0.f, 0.f, 0.f, 0.f};
        #pragma unroll
        for (int k = 0; k < 16; ++k) {
            #pragma unroll
            for (int hh = 0; hh < 4; ++hh) esc[hh] += eav[k] * Wes[k * 4 + hh];
        }
        __half2 p01 = __floats2half2_rn(as4[j].x + esc[0], as4[j].y + esc[1]);
        __half2 p23 = __floats2half2_rn(as4[j].z + esc[2], as4[j].w + esc[3]);
        ry[j] = *reinterpret_cast<int*>(&p01);
        rz[j] = *reinterpret_cast<int*>(&p23);
    }
    __syncthreads();

    // reserve global segments (one atomic per non-empty bucket)
    for (int b = tid; b < NBMAX; b += 512)
        if (cnt[b] > 0) gpos[b] = atomicAdd(&bcur[b * PAD], cnt[b]);
    __syncthreads();

    // flush: line-dense runs within the bucket segment
    #pragma unroll
    for (int j = 0; j < 4; ++j) {
        if (d[j] < 0) continue;
        int g = gpos[((unsigned)d[j]) >> BSH] + rk[j];
        rec_out[g] = make_int4(s[j], ry[j], rz[j], d[j]);
        dl8_out[g] = (unsigned char)(d[j] & 255);
    }
}

// ---------------------------------------------------------------------------
// Kernel 5: per-bucket counting sort to per-node-contiguous order (ONCE per
// bucket, 1024 threads). Emits recs2 (node-grouped) + nstart/ndeg arrays.
// All record traffic is L2/L3-hot (just written by pass1).
// ---------------------------------------------------------------------------
__global__ __launch_bounds__(1024) void k_bin(
    const int* __restrict__ bstart, const int* __restrict__ bcount,
    const int4* __restrict__ recs, const unsigned char* __restrict__ dl8,
    int4* __restrict__ recs2, int* __restrict__ nstart, int* __restrict__ ndeg,
    int n)
{
    __shared__ int cnt[256], st[256], cur[256];
    const int b    = blockIdx.x;
    const int tid  = threadIdx.x;
    const int nbase = b << BSH;
    const int base = bstart[b];
    const int bcnt = bcount[b];

    if (tid < 256) cnt[tid] = 0;
    __syncthreads();

    for (int i = tid; i < bcnt; i += 1024)
        atomicAdd(&cnt[dl8[base + i]], 1);
    __syncthreads();

    if (tid < 64) {
        int c0 = cnt[4 * tid], c1 = cnt[4 * tid + 1];
        int c2 = cnt[4 * tid + 2], c3 = cnt[4 * tid + 3];
        int s = c0 + c1 + c2 + c3;
        int incl = s;
        #pragma unroll
        for (int off = 1; off < 64; off <<= 1) {
            int u = __shfl_up(incl, off, 64);
            if (tid >= off) incl += u;
        }
        int run = incl - s;
        st[4 * tid    ] = run; cur[4 * tid    ] = run; run += c0;
        st[4 * tid + 1] = run; cur[4 * tid + 1] = run; run += c1;
        st[4 * tid + 2] = run; cur[4 * tid + 2] = run; run += c2;
        st[4 * tid + 3] = run; cur[4 * tid + 3] = run;
    }
    __syncthreads();

    if (tid < 256) {
        int node = nbase + tid;
        if (node < n) {
            nstart[node] = base + st[tid];
            ndeg[node]   = cnt[tid];
        }
    }

    for (int i = tid; i < bcnt; i += 1024) {
        int4 r = recs[base + i];
        int p = atomicAdd(&cur[r.w & 255], 1);
        recs2[base + p] = r;
    }
}

// ---------------------------------------------------------------------------
// Kernel 6: wave-per-node aggregation + residual + LayerNorm.
// Records are per-node contiguous: lane-coalesced loads + shfl broadcast.
// No LDS, no binning. 8 h-row gathers in flight.
// ---------------------------------------------------------------------------
__global__ __launch_bounds__(256) void k_agg(
    const int* __restrict__ nstart, const int* __restrict__ ndeg,
    const int4* __restrict__ recs2, const __half* __restrict__ h16,
    const float* __restrict__ a_dst,
    const float* __restrict__ gamma, const float* __restrict__ beta,
    float* __restrict__ out, int n)
{
    int gid  = blockIdx.x * 256 + threadIdx.x;
    int node = gid >> 6;
    int lane = gid & 63;
    if (node >= n) return;
    const int hh   = lane >> 4;
    const int hilo = hh & 1;

    const int rs  = nstart[node];
    const int deg = ndeg[node];

    const float h_node = __half2float(h16[(size_t)node * 64 + lane]);
    float4 ad4 = *(const float4*)(a_dst + (size_t)node * 4);
    const float ad = (hh == 0) ? ad4.x : (hh == 1) ? ad4.y : (hh == 2) ? ad4.z : ad4.w;

    float sum = 0.f, accv = 0.f;

#define PROC_EDGE(HV, YW, ZW)                                            \
    {                                                                    \
        int w_ = (hh < 2) ? (YW) : (ZW);                                 \
        float2 f2_ = __half22float2(*reinterpret_cast<__half2*>(&w_));   \
        float a_ = (hilo ? f2_.y : f2_.x) + ad;                          \
        a_ = (a_ >= 0.f) ? a_ : NEG_SLOPE * a_;                          \
        float w2_ = __expf(a_);                                          \
        sum  += w2_;                                                     \
        accv += w2_ * (HV);                                              \
    }

    for (int b0 = 0; b0 < deg; b0 += 64) {
        int cnt = min(64, deg - b0);
        int4 myc = (b0 + lane < deg) ? recs2[(size_t)rs + b0 + lane]
                                     : make_int4(0, 0, 0, 0);
        int i = 0;
        for (; i + 8 <= cnt; i += 8) {
            int sj[8], yj[8], zj[8];
            float hv[8];
            #pragma unroll
            for (int j = 0; j < 8; ++j) {
                sj[j] = __shfl(myc.x, i + j, 64);
                yj[j] = __shfl(myc.y, i + j, 64);
                zj[j] = __shfl(myc.z, i + j, 64);
            }
            #pragma unroll
            for (int j = 0; j < 8; ++j)
                hv[j] = __half2float(h16[(size_t)sj[j] * 64 + lane]);
            #pragma unroll
            for (int j = 0; j < 8; ++j) PROC_EDGE(hv[j], yj[j], zj[j]);
        }
        for (; i < cnt; ++i) {
            int s0 = __shfl(myc.x, i, 64);
            int y0 = __shfl(myc.y, i, 64);
            int z0 = __shfl(myc.z, i, 64);
            float hv0 = __half2float(h16[(size_t)s0 * 64 + lane]);
            PROC_EDGE(hv0, y0, z0);
        }
    }
#undef PROC_EDGE

    float y = accv / (sum + EPS_SM) + h_node;

    float t1 = y;
    #pragma unroll
    for (int off = 32; off; off >>= 1) t1 += __shfl_xor(t1, off, 64);
    float mu = t1 * (1.f / 64.f);
    float dv = y - mu;
    float vs = dv * dv;
    #pragma unroll
    for (int off = 32; off; off >>= 1) vs += __shfl_xor(vs, off, 64);
    float var = vs * (1.f / 64.f);
    out[(size_t)node * 64 + lane] = dv * rsqrtf(var + EPS_LN) * gamma[lane] + beta[lane];
}

// ---------------------------------------------------------------------------
extern "C" void kernel_launch(void* const* d_in, const int* in_sizes, int n_in,
                              void* d_out, int out_size, void* d_ws, size_t ws_size,
                              hipStream_t stream)
{
    const float* x     = (const float*)d_in[0];
    const int*   ei    = (const int*)  d_in[1];
    const float* ea    = (const float*)d_in[2];
    const float* Wn    = (const float*)d_in[3];
    const float* We    = (const float*)d_in[4];
    const float* asrcW = (const float*)d_in[5];
    const float* adstW = (const float*)d_in[6];
    const float* gamma = (const float*)d_in[7];
    const float* beta  = (const float*)d_in[8];
    float* out = (float*)d_out;

    const int n = in_sizes[0] / 64;
    const int E = in_sizes[1] / 2;
    const int* src = ei;
    const int* dst = ei + E;
    const int NB = (n + 255) >> BSH;
    const int nchunk = (E + CHUNK - 1) / CHUNK;

    float* ws = (float*)d_ws;
    size_t off = 0;
    __half* h16  = (__half*)(ws + off); off += (size_t)n * 32;   // n*64 halves
    float* a_src = ws + off; off += (size_t)n * 4;
    float* a_dst = ws + off; off += (size_t)n * 4;
    int4* recs   = (int4*)(ws + off); off += (size_t)E * 4;
    int4* recs2  = (int4*)(ws + off); off += (size_t)E * 4;
    unsigned char* dl8 = (unsigned char*)(ws + off); off += ((size_t)E + 3) / 4;
    int* ibase  = (int*)(ws + off);
    int* gbcnt  = ibase;                       // NBMAX*PAD
    int* bcur   = ibase + NBMAX * PAD;         // NBMAX*PAD
    int* bstart = ibase + 2 * NBMAX * PAD;     // NBMAX
    int* bcount = bstart + NBMAX;              // NBMAX
    int* nstart = bcount + NBMAX;              // n
    int* ndeg   = nstart + n;                  // n

    hipMemsetAsync(gbcnt, 0, (size_t)NBMAX * PAD * sizeof(int), stream);

    k_node<<<(n + 63) / 64, 256, 0, stream>>>(x, Wn, asrcW, adstW, h16, a_src, a_dst, n);
    k_bhist<<<nchunk, 256, 0, stream>>>(dst, gbcnt, E);
    k_bscan<<<1, 64, 0, stream>>>(gbcnt, bstart, bcount, bcur);
    k_pass1<<<nchunk, 512, 0, stream>>>(src, dst, ea, We, a_src, bcur, recs, dl8, E);
    k_bin<<<NB, 1024, 0, stream>>>(bstart, bcount, recs, dl8, recs2, nstart, ndeg, n);
    k_agg<<<((size_t)n * 64 + 255) / 256, 256, 0, stream>>>(
        nstart, ndeg, recs2, h16, a_dst, gamma, beta, out, n);
}

// Round 12
// 193.828 us; speedup vs baseline: 1.7089x; 1.0257x over previous
//
#include <hip/hip_runtime.h>
#include <hip/hip_fp16.h>
#include <math.h>

#define NEG_SLOPE 0.2f
#define EPS_SM 1e-8f
#define EPS_LN 1e-5f
#define PAD 16          // one global counter per 64B line
#define BSH 8           // bucket = dst >> 8  (256 nodes/bucket)
#define NBMAX 512       // max buckets (n <= 131072)
#define CHUNK 2048      // edges per pass1/bhist block

// round-to-nearest bf16 pair pack: returns (bf16(b)<<16) | bf16(a)
__device__ inline unsigned bf16pair(float a, float b)
{
    unsigned ua = __float_as_uint(a), ub = __float_as_uint(b);
    ua = (ua + 0x7fffu + ((ua >> 16) & 1u)) >> 16;
    ub = (ub + 0x7fffu + ((ub >> 16) & 1u)) >> 16;
    return ua | (ub << 16);
}

// ---------------------------------------------------------------------------
// Kernel 1: h = x @ W_node (64x64) + fused a_src/a_dst projections.
// 64 rows per 256-thread block, register-tiled 4x4 per thread. h stored f16.
// ---------------------------------------------------------------------------
__global__ __launch_bounds__(256) void k_node(
    const float* __restrict__ x, const float* __restrict__ Wn,
    const float* __restrict__ attn_src, const float* __restrict__ attn_dst,
    __half* __restrict__ h16, float* __restrict__ a_src, float* __restrict__ a_dst,
    int n)
{
    __shared__ float Ws[64][64];   // W[k][col]
    __shared__ float xs[64][64];   // x[r][k]
    const int tid  = threadIdx.x;
    const int row0 = blockIdx.x * 64;

    const float4* Wn4 = (const float4*)Wn;
    #pragma unroll
    for (int i = tid; i < 1024; i += 256) {
        float4 v = Wn4[i];
        *(float4*)&Ws[i >> 4][(i & 15) * 4] = v;
    }
    const float4* x4 = (const float4*)x;
    #pragma unroll
    for (int i = tid; i < 1024; i += 256) {
        int r  = i >> 4;
        int gr = row0 + r;
        float4 v = (gr < n) ? x4[(size_t)gr * 16 + (i & 15)]
                            : make_float4(0.f, 0.f, 0.f, 0.f);
        *(float4*)&xs[r][(i & 15) * 4] = v;
    }
    __syncthreads();

    const int c4 = tid & 15;
    const int r4 = tid >> 4;

    float4 acc0 = make_float4(0.f, 0.f, 0.f, 0.f);
    float4 acc1 = make_float4(0.f, 0.f, 0.f, 0.f);
    float4 acc2 = make_float4(0.f, 0.f, 0.f, 0.f);
    float4 acc3 = make_float4(0.f, 0.f, 0.f, 0.f);

    #pragma unroll 8
    for (int k = 0; k < 64; ++k) {
        float4 w = *(const float4*)&Ws[k][c4 * 4];
        float x0 = xs[r4     ][k];
        float x1 = xs[r4 + 16][k];
        float x2 = xs[r4 + 32][k];
        float x3 = xs[r4 + 48][k];
        acc0.x += x0 * w.x; acc0.y += x0 * w.y; acc0.z += x0 * w.z; acc0.w += x0 * w.w;
        acc1.x += x1 * w.x; acc1.y += x1 * w.y; acc1.z += x1 * w.z; acc1.w += x1 * w.w;
        acc2.x += x2 * w.x; acc2.y += x2 * w.y; acc2.z += x2 * w.z; acc2.w += x2 * w.w;
        acc3.x += x3 * w.x; acc3.y += x3 * w.y; acc3.z += x3 * w.z; acc3.w += x3 * w.w;
    }

    const float4 asw = *(const float4*)&attn_src[c4 * 4];
    const float4 adw = *(const float4*)&attn_dst[c4 * 4];
    const int hh = c4 >> 2;
    const bool writer = (c4 & 3) == 0;

    float4 accs[4] = {acc0, acc1, acc2, acc3};
    #pragma unroll
    for (int j = 0; j < 4; ++j) {
        int gr = row0 + r4 + 16 * j;
        if (gr < n) {
            __half2 p0 = __floats2half2_rn(accs[j].x, accs[j].y);
            __half2 p1 = __floats2half2_rn(accs[j].z, accs[j].w);
            uint2 pk = make_uint2(*reinterpret_cast<unsigned*>(&p0),
                                  *reinterpret_cast<unsigned*>(&p1));
            *(uint2*)&h16[(size_t)gr * 64 + c4 * 4] = pk;
            float ps = accs[j].x * asw.x + accs[j].y * asw.y +
                       accs[j].z * asw.z + accs[j].w * asw.w;
            float pd = accs[j].x * adw.x + accs[j].y * adw.y +
                       accs[j].z * adw.z + accs[j].w * adw.w;
            ps += __shfl_xor(ps, 1, 64); ps += __shfl_xor(ps, 2, 64);
            pd += __shfl_xor(pd, 1, 64); pd += __shfl_xor(pd, 2, 64);
            if (writer) {
                a_src[(size_t)gr * 4 + hh] = ps;
                a_dst[(size_t)gr * 4 + hh] = pd;
            }
        } else {
            float ps = 0.f, pd = 0.f;
            ps += __shfl_xor(ps, 1, 64); ps += __shfl_xor(ps, 2, 64);
            pd += __shfl_xor(pd, 1, 64); pd += __shfl_xor(pd, 2, 64);
        }
    }
}

// ---------------------------------------------------------------------------
// Kernel 2: bucket histogram (LDS-staged, one global add per (chunk,bucket)).
// ---------------------------------------------------------------------------
__global__ __launch_bounds__(256) void k_bhist(
    const int* __restrict__ dst, int* __restrict__ gbcnt, int E)
{
    __shared__ int cnt[NBMAX];
    const int tid = threadIdx.x;
    for (int i = tid; i < NBMAX; i += 256) cnt[i] = 0;
    __syncthreads();
    const int e0 = blockIdx.x * CHUNK;
    const int ce = min(CHUNK, E - e0);
    for (int j = tid; j < ce; j += 256)
        atomicAdd(&cnt[((unsigned)dst[e0 + j]) >> BSH], 1);
    __syncthreads();
    for (int b = tid; b < NBMAX; b += 256)
        if (cnt[b] > 0) atomicAdd(&gbcnt[b * PAD], cnt[b]);
}

// ---------------------------------------------------------------------------
// Kernel 3: exclusive scan of 512 bucket counts (one wave).
// ---------------------------------------------------------------------------
__global__ void k_bscan(const int* __restrict__ gbcnt,
                        int* __restrict__ bstart, int* __restrict__ bcount,
                        int* __restrict__ bcur)
{
    int lane = threadIdx.x;   // 64 threads
    int c[8]; int s = 0;
    #pragma unroll
    for (int j = 0; j < 8; ++j) { c[j] = gbcnt[(lane * 8 + j) * PAD]; s += c[j]; }
    int incl = s;
    #pragma unroll
    for (int off = 1; off < 64; off <<= 1) {
        int u = __shfl_up(incl, off, 64);
        if (lane >= off) incl += u;
    }
    int run = incl - s;
    #pragma unroll
    for (int j = 0; j < 8; ++j) {
        int b = lane * 8 + j;
        bstart[b] = run;
        bcount[b] = c[j];
        bcur[b * PAD] = run;
        run += c[j];
    }
}

// ---------------------------------------------------------------------------
// Kernel 4: bucket-grouped scatter. 512 threads, 4 edges/thread.
// Record: int4 { src, f16x2(as01+esc01), f16x2(as23+esc23), dst }.
// ---------------------------------------------------------------------------
__global__ __launch_bounds__(512) void k_pass1(
    const int* __restrict__ src, const int* __restrict__ dst,
    const float* __restrict__ ea, const float* __restrict__ We,
    const float* __restrict__ a_src,
    int* __restrict__ bcur, int4* __restrict__ rec_out,
    unsigned char* __restrict__ dl8_out, int E)
{
    __shared__ float Wes[64];       // W_edge [16][4]
    __shared__ int cnt[NBMAX];      // 2KB
    __shared__ int gpos[NBMAX];     // 2KB
    const int tid = threadIdx.x;
    if (tid < 64) Wes[tid] = We[tid];
    for (int i = tid; i < NBMAX; i += 512) cnt[i] = 0;
    __syncthreads();

    const int e0 = blockIdx.x * CHUNK;
    int d[4], s[4], rk[4];
    #pragma unroll
    for (int j = 0; j < 4; ++j) {
        int e = e0 + j * 512 + tid;
        bool v = e < E;
        d[j] = v ? dst[e] : -1;
        s[j] = v ? src[e] : 0;
    }

    #pragma unroll
    for (int j = 0; j < 4; ++j)
        rk[j] = (d[j] >= 0) ? atomicAdd(&cnt[((unsigned)d[j]) >> BSH], 1) : 0;

    float4 as4[4];
    #pragma unroll
    for (int j = 0; j < 4; ++j)
        as4[j] = (d[j] >= 0) ? *(const float4*)(a_src + (size_t)s[j] * 4)
                             : make_float4(0.f, 0.f, 0.f, 0.f);

    int ry[4], rz[4];
    #pragma unroll
    for (int j = 0; j < 4; ++j) {
        if (d[j] < 0) { ry[j] = 0; rz[j] = 0; continue; }
        int e = e0 + j * 512 + tid;
        const float4* ea4 = (const float4*)(ea + (size_t)e * 16);
        float4 q0 = ea4[0], q1 = ea4[1], q2 = ea4[2], q3 = ea4[3];
        float eav[16] = {q0.x, q0.y, q0.z, q0.w, q1.x, q1.y, q1.z, q1.w,
                         q2.x, q2.y, q2.z, q2.w, q3.x, q3.y, q3.z, q3.w};
        float esc[4] = {0.f, 0.f, 0.f, 0.f};
        #pragma unroll
        for (int k = 0; k < 16; ++k) {
            #pragma unroll
            for (int hh = 0; hh < 4; ++hh) esc[hh] += eav[k] * Wes[k * 4 + hh];
        }
        __half2 p01 = __floats2half2_rn(as4[j].x + esc[0], as4[j].y + esc[1]);
        __half2 p23 = __floats2half2_rn(as4[j].z + esc[2], as4[j].w + esc[3]);
        ry[j] = *reinterpret_cast<int*>(&p01);
        rz[j] = *reinterpret_cast<int*>(&p23);
    }
    __syncthreads();

    for (int b = tid; b < NBMAX; b += 512)
        if (cnt[b] > 0) gpos[b] = atomicAdd(&bcur[b * PAD], cnt[b]);
    __syncthreads();

    #pragma unroll
    for (int j = 0; j < 4; ++j) {
        if (d[j] < 0) continue;
        int g = gpos[((unsigned)d[j]) >> BSH] + rk[j];
        rec_out[g] = make_int4(s[j], ry[j], rz[j], d[j]);
        dl8_out[g] = (unsigned char)(d[j] & 255);
    }
}

// ---------------------------------------------------------------------------
// Kernel 5: per-bucket counting sort to per-node-contiguous order + FUSED
// attention-weight computation: w = exp(lrelu(a_srcesc + a_dst)) per head,
// stored as bf16x4 (bf16: exp can reach ~e^35, overflows f16, fits bf16).
// recs2 record: int4 { src, bf16x2(w0,w1), bf16x2(w2,w3), dst }.
// a_dst gathers are bucket-local (256 nodes, 4KB) => L2-hot.
// ---------------------------------------------------------------------------
__global__ __launch_bounds__(1024) void k_bin(
    const int* __restrict__ bstart, const int* __restrict__ bcount,
    const int4* __restrict__ recs, const unsigned char* __restrict__ dl8,
    const float* __restrict__ a_dst,
    int4* __restrict__ recs2, int* __restrict__ nstart, int* __restrict__ ndeg,
    int n)
{
    __shared__ int cnt[256], st[256], cur[256];
    const int b    = blockIdx.x;
    const int tid  = threadIdx.x;
    const int nbase = b << BSH;
    const int base = bstart[b];
    const int bcnt = bcount[b];

    if (tid < 256) cnt[tid] = 0;
    __syncthreads();

    for (int i = tid; i < bcnt; i += 1024)
        atomicAdd(&cnt[dl8[base + i]], 1);
    __syncthreads();

    if (tid < 64) {
        int c0 = cnt[4 * tid], c1 = cnt[4 * tid + 1];
        int c2 = cnt[4 * tid + 2], c3 = cnt[4 * tid + 3];
        int s = c0 + c1 + c2 + c3;
        int incl = s;
        #pragma unroll
        for (int off = 1; off < 64; off <<= 1) {
            int u = __shfl_up(incl, off, 64);
            if (tid >= off) incl += u;
        }
        int run = incl - s;
        st[4 * tid    ] = run; cur[4 * tid    ] = run; run += c0;
        st[4 * tid + 1] = run; cur[4 * tid + 1] = run; run += c1;
        st[4 * tid + 2] = run; cur[4 * tid + 2] = run; run += c2;
        st[4 * tid + 3] = run; cur[4 * tid + 3] = run;
    }
    __syncthreads();

    if (tid < 256) {
        int node = nbase + tid;
        if (node < n) {
            nstart[node] = base + st[tid];
            ndeg[node]   = cnt[tid];
        }
    }

    for (int i = tid; i < bcnt; i += 1024) {
        int4 r = recs[base + i];
        int dl = r.w & 255;
        // a = a_srcesc (f16) + a_dst; w = exp(lrelu(a)) -> bf16
        float4 ad4 = *(const float4*)(a_dst + (size_t)(nbase + dl) * 4);
        float2 a01 = __half22float2(*reinterpret_cast<__half2*>(&r.y));
        float2 a23 = __half22float2(*reinterpret_cast<__half2*>(&r.z));
        float a0 = a01.x + ad4.x, a1 = a01.y + ad4.y;
        float a2 = a23.x + ad4.z, a3 = a23.y + ad4.w;
        a0 = (a0 >= 0.f) ? a0 : NEG_SLOPE * a0;
        a1 = (a1 >= 0.f) ? a1 : NEG_SLOPE * a1;
        a2 = (a2 >= 0.f) ? a2 : NEG_SLOPE * a2;
        a3 = (a3 >= 0.f) ? a3 : NEG_SLOPE * a3;
        unsigned w01 = bf16pair(__expf(a0), __expf(a1));
        unsigned w23 = bf16pair(__expf(a2), __expf(a3));
        int p = atomicAdd(&cur[dl], 1);
        recs2[base + p] = make_int4(r.x, (int)w01, (int)w23, r.w);
    }
}

// ---------------------------------------------------------------------------
// Kernel 6: wave-per-node aggregation + residual + LayerNorm.
// Records carry precomputed bf16 attention weights: per edge only
// {3 shfl, select, 2 bit-ops, fma, add, h16 cvt} — no exp/lrelu/a_dst.
// ---------------------------------------------------------------------------
__global__ __launch_bounds__(256) void k_agg(
    const int* __restrict__ nstart, const int* __restrict__ ndeg,
    const int4* __restrict__ recs2, const __half* __restrict__ h16,
    const float* __restrict__ gamma, const float* __restrict__ beta,
    float* __restrict__ out, int n)
{
    int gid  = blockIdx.x * 256 + threadIdx.x;
    int node = gid >> 6;
    int lane = gid & 63;
    if (node >= n) return;
    const int hh   = lane >> 4;
    const int wsh  = (hh & 1) ? 0 : 16;   // bf16 lane-slot shift

    const unsigned rs = (unsigned)nstart[node];
    const int deg = ndeg[node];

    const float h_node = __half2float(h16[((unsigned)node << 6) | lane]);

    float sum = 0.f, accv = 0.f;

#define PROC_EDGE(HV, YW, ZW)                                            \
    {                                                                    \
        int w_ = (hh < 2) ? (YW) : (ZW);                                 \
        float wf_ = __int_as_float(((unsigned)w_ << wsh) & 0xffff0000u); \
        sum  += wf_;                                                     \
        accv += wf_ * (HV);                                              \
    }

    for (int b0 = 0; b0 < deg; b0 += 64) {
        int cnt = min(64, deg - b0);
        int4 myc = (b0 + lane < deg) ? recs2[rs + b0 + lane]
                                     : make_int4(0, 0, 0, 0);
        int i = 0;
        for (; i + 8 <= cnt; i += 8) {
            int sj[8], yj[8], zj[8];
            float hv[8];
            #pragma unroll
            for (int j = 0; j < 8; ++j) {
                sj[j] = __shfl(myc.x, i + j, 64);
                yj[j] = __shfl(myc.y, i + j, 64);
                zj[j] = __shfl(myc.z, i + j, 64);
            }
            #pragma unroll
            for (int j = 0; j < 8; ++j)
                hv[j] = __half2float(h16[((unsigned)sj[j] << 6) | lane]);
            #pragma unroll
            for (int j = 0; j < 8; ++j) PROC_EDGE(hv[j], yj[j], zj[j]);
        }
        for (; i < cnt; ++i) {
            int s0 = __shfl(myc.x, i, 64);
            int y0 = __shfl(myc.y, i, 64);
            int z0 = __shfl(myc.z, i, 64);
            float hv0 = __half2float(h16[((unsigned)s0 << 6) | lane]);
            PROC_EDGE(hv0, y0, z0);
        }
    }
#undef PROC_EDGE

    float y = accv / (sum + EPS_SM) + h_node;

    float t1 = y;
    #pragma unroll
    for (int off = 32; off; off >>= 1) t1 += __shfl_xor(t1, off, 64);
    float mu = t1 * (1.f / 64.f);
    float dv = y - mu;
    float vs = dv * dv;
    #pragma unroll
    for (int off = 32; off; off >>= 1) vs += __shfl_xor(vs, off, 64);
    float var = vs * (1.f / 64.f);
    out[((unsigned)node << 6) | lane] =
        dv * rsqrtf(var + EPS_LN) * gamma[lane] + beta[lane];
}

// ---------------------------------------------------------------------------
extern "C" void kernel_launch(void* const* d_in, const int* in_sizes, int n_in,
                              void* d_out, int out_size, void* d_ws, size_t ws_size,
                              hipStream_t stream)
{
    const float* x     = (const float*)d_in[0];
    const int*   ei    = (const int*)  d_in[1];
    const float* ea    = (const float*)d_in[2];
    const float* Wn    = (const float*)d_in[3];
    const float* We    = (const float*)d_in[4];
    const float* asrcW = (const float*)d_in[5];
    const float* adstW = (const float*)d_in[6];
    const float* gamma = (const float*)d_in[7];
    const float* beta  = (const float*)d_in[8];
    float* out = (float*)d_out;

    const int n = in_sizes[0] / 64;
    const int E = in_sizes[1] / 2;
    const int* src = ei;
    const int* dst = ei + E;
    const int NB = (n + 255) >> BSH;
    const int nchunk = (E + CHUNK - 1) / CHUNK;

    float* ws = (float*)d_ws;
    size_t off = 0;
    __half* h16  = (__half*)(ws + off); off += (size_t)n * 32;   // n*64 halves
    float* a_src = ws + off; off += (size_t)n * 4;
    float* a_dst = ws + off; off += (size_t)n * 4;
    int4* recs   = (int4*)(ws + off); off += (size_t)E * 4;
    int4* recs2  = (int4*)(ws + off); off += (size_t)E * 4;
    unsigned char* dl8 = (unsigned char*)(ws + off); off += ((size_t)E + 3) / 4;
    int* ibase  = (int*)(ws + off);
    int* gbcnt  = ibase;                       // NBMAX*PAD
    int* bcur   = ibase + NBMAX * PAD;         // NBMAX*PAD
    int* bstart = ibase + 2 * NBMAX * PAD;     // NBMAX
    int* bcount = bstart + NBMAX;              // NBMAX
    int* nstart = bcount + NBMAX;              // n
    int* ndeg   = nstart + n;                  // n

    hipMemsetAsync(gbcnt, 0, (size_t)NBMAX * PAD * sizeof(int), stream);

    k_node<<<(n + 63) / 64, 256, 0, stream>>>(x, Wn, asrcW, adstW, h16, a_src, a_dst, n);
    k_bhist<<<nchunk, 256, 0, stream>>>(dst, gbcnt, E);
    k_bscan<<<1, 64, 0, stream>>>(gbcnt, bstart, bcount, bcur);
    k_pass1<<<nchunk, 512, 0, stream>>>(src, dst, ea, We, a_src, bcur, recs, dl8, E);
    k_bin<<<NB, 1024, 0, stream>>>(bstart, bcount, recs, dl8, a_dst, recs2,
                                   nstart, ndeg, n);
    k_agg<<<((size_t)n * 64 + 255) / 256, 256, 0, stream>>>(
        nstart, ndeg, recs2, h16, gamma, beta, out, n);
}